// Round 1
// baseline (1614.002 us; speedup 1.0000x reference)
//
#include <hip/hip_runtime.h>

// GraphConv: deg -> norm -> scatter-add(feat[src]*norm[src] -> agg[dst]) -> agg@W*norm+bias
// Round 0: correctness-first pipeline.
//   d_out doubles as the agg accumulator (same size as output), GEMM runs in-place.
//   d_ws holds deg/norm (N floats).

constexpr int N_NODES = 100000;
constexpr int D = 128;

__global__ void k_deg(const int* __restrict__ dst, int E, float* __restrict__ deg) {
    int i = blockIdx.x * blockDim.x + threadIdx.x;
    if (i < E) atomicAdd(deg + dst[i], 1.0f);
}

__global__ void k_norm(float* __restrict__ dn) {
    int i = blockIdx.x * blockDim.x + threadIdx.x;
    if (i < N_NODES) dn[i] = rsqrtf(fmaxf(dn[i], 1.0f));
}

// One 64-lane wave per edge; each lane handles 2 consecutive floats of the 128-wide row.
__global__ void k_scatter(const float* __restrict__ feat, const int* __restrict__ src,
                          const int* __restrict__ dst, const float* __restrict__ norm,
                          int E, float* __restrict__ agg) {
    long long gtid = (long long)blockIdx.x * blockDim.x + threadIdx.x;
    int e    = (int)(gtid >> 6);
    int lane = (int)(gtid & 63);
    if (e >= E) return;
    int s = src[e];
    int t = dst[e];
    float ns = norm[s];
    float2 v = ((const float2*)(feat + (size_t)s * D))[lane];
    float* arow = agg + (size_t)t * D + lane * 2;
    atomicAdd(arow + 0, v.x * ns);
    atomicAdd(arow + 1, v.y * ns);
}

// In-place rst = (agg @ W) * norm + bias.  W (64KB) staged in LDS; 2 rows / block-iteration.
__global__ __launch_bounds__(256) void k_gemm(float* __restrict__ io,
                                              const float* __restrict__ W,
                                              const float* __restrict__ bias,
                                              const float* __restrict__ norm) {
    __shared__ float sW[D * D];      // 64 KB
    __shared__ float srow[2][D];
    for (int i = threadIdx.x; i < D * D; i += 256) sW[i] = W[i];

    const int r = threadIdx.x >> 7;       // 0..1  (row within pair)
    const int c = threadIdx.x & 127;      // 0..127 (output column)
    const float bc = bias[c];

    const int npairs = N_NODES / 2;
    for (int rp = blockIdx.x; rp < npairs; rp += gridDim.x) {
        __syncthreads();                  // sW ready (iter 0) / srow no longer read (iter>0)
        const int row = rp * 2 + r;
        srow[r][c] = io[(size_t)row * D + c];
        __syncthreads();
        float acc = 0.f;
        #pragma unroll 8
        for (int k = 0; k < D; ++k)
            acc = fmaf(srow[r][k], sW[k * D + c], acc);
        io[(size_t)row * D + c] = acc * norm[row] + bc;
    }
}

extern "C" void kernel_launch(void* const* d_in, const int* in_sizes, int n_in,
                              void* d_out, int out_size, void* d_ws, size_t ws_size,
                              hipStream_t stream) {
    const float* feat   = (const float*)d_in[0];
    const float* weight = (const float*)d_in[1];
    const float* bias   = (const float*)d_in[2];
    const int*   src    = (const int*)d_in[3];
    const int*   dst    = (const int*)d_in[4];
    const int E = in_sizes[3];

    float* agg  = (float*)d_out;          // accumulate in-place in output buffer
    float* norm = (float*)d_ws;           // N floats: deg, then norm in-place

    hipMemsetAsync(d_out, 0, (size_t)N_NODES * D * sizeof(float), stream);
    hipMemsetAsync(norm, 0, (size_t)N_NODES * sizeof(float), stream);

    k_deg<<<(E + 255) / 256, 256, 0, stream>>>(dst, E, norm);
    k_norm<<<(N_NODES + 255) / 256, 256, 0, stream>>>(norm);

    // one wave per edge -> E*64 threads
    long long sthreads = (long long)E * 64;
    int sblocks = (int)((sthreads + 255) / 256);
    k_scatter<<<sblocks, 256, 0, stream>>>(feat, src, dst, norm, E, agg);

    k_gemm<<<4096, 256, 0, stream>>>(agg, weight, bias, norm);
}

// Round 2
// 524.149 us; speedup vs baseline: 3.0793x; 3.0793x over previous
//
#include <hip/hip_runtime.h>

// GraphConv: deg -> norm -> CSR-bucket by dst -> gather-sum(feat[src]*norm[src]) -> agg@W*norm+bias
// Round 1: replace 205M fp32 atomics (1300us, atomic-RMW-bound) with on-the-fly CSR + register gather.

constexpr int N_NODES = 100000;
constexpr int D = 128;
constexpr int SCAN_CHUNK = 1024;                          // elems per scan block
constexpr int NBLK_SCAN = (N_NODES + SCAN_CHUNK - 1) / SCAN_CHUNK;   // 98

// ---------------- degree / norm ----------------
__global__ void k_deg(const int* __restrict__ dst, int E, int* __restrict__ deg) {
    int i = blockIdx.x * blockDim.x + threadIdx.x;
    if (i < E) atomicAdd(deg + dst[i], 1);
}

__global__ void k_norm(const int* __restrict__ deg, float* __restrict__ norm) {
    int i = blockIdx.x * blockDim.x + threadIdx.x;
    if (i < N_NODES) norm[i] = rsqrtf(fmaxf((float)deg[i], 1.0f));
}

// ---------------- 3-phase exclusive scan of deg -> offsets ----------------
__global__ __launch_bounds__(256) void k_scan1(const int* __restrict__ deg, int* __restrict__ part) {
    __shared__ int lds[256];
    int base = blockIdx.x * SCAN_CHUNK;
    int t = threadIdx.x;
    int s = 0;
    #pragma unroll
    for (int j = 0; j < 4; ++j) {
        int i = base + t * 4 + j;
        if (i < N_NODES) s += deg[i];
    }
    lds[t] = s; __syncthreads();
    for (int off = 128; off > 0; off >>= 1) {
        if (t < off) lds[t] += lds[t + off];
        __syncthreads();
    }
    if (t == 0) part[blockIdx.x] = lds[0];
}

__global__ void k_scan2(int* __restrict__ part) {   // serial exclusive scan of 98 partials
    if (threadIdx.x == 0 && blockIdx.x == 0) {
        int run = 0;
        for (int i = 0; i < NBLK_SCAN; ++i) { int v = part[i]; part[i] = run; run += v; }
    }
}

__global__ __launch_bounds__(256) void k_scan3(const int* __restrict__ deg, const int* __restrict__ part,
                                               int* __restrict__ offs, int* __restrict__ curs) {
    __shared__ int lds[256];
    int base = blockIdx.x * SCAN_CHUNK;
    int t = threadIdx.x;
    int v[4]; int s = 0;
    #pragma unroll
    for (int j = 0; j < 4; ++j) {
        int i = base + t * 4 + j;
        v[j] = (i < N_NODES) ? deg[i] : 0;
        s += v[j];
    }
    lds[t] = s; __syncthreads();
    // Hillis-Steele inclusive scan
    for (int off = 1; off < 256; off <<= 1) {
        int x = (t >= off) ? lds[t - off] : 0;
        __syncthreads();
        lds[t] += x;
        __syncthreads();
    }
    int run = part[blockIdx.x] + lds[t] - s;   // exclusive prefix for this thread's 4 elems
    #pragma unroll
    for (int j = 0; j < 4; ++j) {
        int i = base + t * 4 + j;
        if (i < N_NODES) { offs[i] = run; curs[i] = run; }
        run += v[j];
    }
}

// ---------------- bucket edges by dst ----------------
__global__ void k_bucket(const int* __restrict__ src, const int* __restrict__ dst, int E,
                         int* __restrict__ curs, int* __restrict__ esrc) {
    int i = blockIdx.x * blockDim.x + threadIdx.x;
    if (i < E) {
        int pos = atomicAdd(curs + dst[i], 1);
        esrc[pos] = src[i];
    }
}

// ---------------- gather: one wave per dst node ----------------
__global__ __launch_bounds__(256) void k_gather(const float* __restrict__ feat,
                                                const float* __restrict__ norm,
                                                const int* __restrict__ offs,
                                                const int* __restrict__ deg,
                                                const int* __restrict__ esrc,
                                                float* __restrict__ agg) {
    int gtid = blockIdx.x * blockDim.x + threadIdx.x;
    int node = gtid >> 6;            // one 64-lane wave per node
    int lane = gtid & 63;            // lane handles float2 at col lane*2
    if (node >= N_NODES) return;
    int start = offs[node];
    int cnt   = deg[node];
    float2 acc = {0.f, 0.f};
    const float2* feat2 = (const float2*)feat;
    int j = 0;
    for (; j + 2 <= cnt; j += 2) {          // 2-edge unroll for ILP
        int s0 = esrc[start + j];
        int s1 = esrc[start + j + 1];
        float n0 = norm[s0], n1 = norm[s1];
        float2 v0 = feat2[(size_t)s0 * 64 + lane];
        float2 v1 = feat2[(size_t)s1 * 64 + lane];
        acc.x = fmaf(v0.x, n0, acc.x); acc.y = fmaf(v0.y, n0, acc.y);
        acc.x = fmaf(v1.x, n1, acc.x); acc.y = fmaf(v1.y, n1, acc.y);
    }
    if (j < cnt) {
        int s0 = esrc[start + j];
        float n0 = norm[s0];
        float2 v0 = feat2[(size_t)s0 * 64 + lane];
        acc.x = fmaf(v0.x, n0, acc.x); acc.y = fmaf(v0.y, n0, acc.y);
    }
    ((float2*)agg)[(size_t)node * 64 + lane] = acc;
}

// ---------------- fallback scatter (round 0) ----------------
__global__ void k_scatter(const float* __restrict__ feat, const int* __restrict__ src,
                          const int* __restrict__ dst, const float* __restrict__ norm,
                          int E, float* __restrict__ agg) {
    long long gtid = (long long)blockIdx.x * blockDim.x + threadIdx.x;
    int e    = (int)(gtid >> 6);
    int lane = (int)(gtid & 63);
    if (e >= E) return;
    int s = src[e];
    int t = dst[e];
    float ns = norm[s];
    float2 v = ((const float2*)(feat + (size_t)s * D))[lane];
    float* arow = agg + (size_t)t * D + lane * 2;
    atomicAdd(arow + 0, v.x * ns);
    atomicAdd(arow + 1, v.y * ns);
}

__global__ void k_deg_f(const int* __restrict__ dst, int E, float* __restrict__ deg) {
    int i = blockIdx.x * blockDim.x + threadIdx.x;
    if (i < E) atomicAdd(deg + dst[i], 1.0f);
}
__global__ void k_norm_f(float* __restrict__ dn) {
    int i = blockIdx.x * blockDim.x + threadIdx.x;
    if (i < N_NODES) dn[i] = rsqrtf(fmaxf(dn[i], 1.0f));
}

// ---------------- in-place GEMM epilogue ----------------
__global__ __launch_bounds__(256) void k_gemm(float* __restrict__ io,
                                              const float* __restrict__ W,
                                              const float* __restrict__ bias,
                                              const float* __restrict__ norm) {
    __shared__ float sW[D * D];      // 64 KB
    __shared__ float srow[2][D];
    for (int i = threadIdx.x; i < D * D; i += 256) sW[i] = W[i];

    const int r = threadIdx.x >> 7;
    const int c = threadIdx.x & 127;
    const float bc = bias[c];

    const int npairs = N_NODES / 2;
    for (int rp = blockIdx.x; rp < npairs; rp += gridDim.x) {
        __syncthreads();
        const int row = rp * 2 + r;
        srow[r][c] = io[(size_t)row * D + c];
        __syncthreads();
        float acc = 0.f;
        #pragma unroll 8
        for (int k = 0; k < D; ++k)
            acc = fmaf(srow[r][k], sW[k * D + c], acc);
        io[(size_t)row * D + c] = acc * norm[row] + bc;
    }
}

extern "C" void kernel_launch(void* const* d_in, const int* in_sizes, int n_in,
                              void* d_out, int out_size, void* d_ws, size_t ws_size,
                              hipStream_t stream) {
    const float* feat   = (const float*)d_in[0];
    const float* weight = (const float*)d_in[1];
    const float* bias   = (const float*)d_in[2];
    const int*   src    = (const int*)d_in[3];
    const int*   dst    = (const int*)d_in[4];
    const int E = in_sizes[3];

    float* agg = (float*)d_out;

    // workspace layout
    float* norm = (float*)d_ws;                 // N floats
    int*   deg  = (int*)(norm + N_NODES);       // N ints
    int*   offs = deg + N_NODES;                // N ints
    int*   curs = offs + N_NODES;               // N ints
    int*   part = curs + N_NODES;               // 128 ints
    int*   esrc = part + 128;                   // E ints
    size_t need = ((size_t)4 * N_NODES + 128 + (size_t)E) * 4;

    if (ws_size >= need) {
        hipMemsetAsync(deg, 0, (size_t)N_NODES * sizeof(int), stream);
        k_deg<<<(E + 255) / 256, 256, 0, stream>>>(dst, E, deg);
        k_norm<<<(N_NODES + 255) / 256, 256, 0, stream>>>(deg, norm);
        k_scan1<<<NBLK_SCAN, 256, 0, stream>>>(deg, part);
        k_scan2<<<1, 64, 0, stream>>>(part);
        k_scan3<<<NBLK_SCAN, 256, 0, stream>>>(deg, part, offs, curs);
        k_bucket<<<(E + 255) / 256, 256, 0, stream>>>(src, dst, E, curs, esrc);
        // one wave per node
        long long gthreads = (long long)N_NODES * 64;
        k_gather<<<(int)((gthreads + 255) / 256), 256, 0, stream>>>(feat, norm, offs, deg, esrc, agg);
    } else {
        // fallback: atomic scatter (round-0 path)
        hipMemsetAsync(d_out, 0, (size_t)N_NODES * D * sizeof(float), stream);
        hipMemsetAsync(norm, 0, (size_t)N_NODES * sizeof(float), stream);
        k_deg_f<<<(E + 255) / 256, 256, 0, stream>>>(dst, E, norm);
        k_norm_f<<<(N_NODES + 255) / 256, 256, 0, stream>>>(norm);
        long long sthreads = (long long)E * 64;
        k_scatter<<<(int)((sthreads + 255) / 256), 256, 0, stream>>>(feat, src, dst, norm, E, agg);
    }

    k_gemm<<<4096, 256, 0, stream>>>(agg, weight, bias, norm);
}

// Round 3
// 366.338 us; speedup vs baseline: 4.4058x; 1.4308x over previous
//
#include <hip/hip_runtime.h>

// GraphConv: deg -> norm -> CSR-bucket by dst -> gather-sum(feat[src]*norm[src]) -> agg@W*norm+bias
// Round 2: replace scalar-FMA GEMM (218us, LDS-read/VALU-bound) with split-bf16 MFMA GEMM.
//          A = A_hi + A_lo (bf16), W = W_hi + W_lo (bf16, pre-packed in fragment order);
//          A@W ~= A_hi@W_hi + A_lo@W_hi + A_hi@W_lo accumulated in fp32 MFMA.

constexpr int N_NODES = 100000;
constexpr int D = 128;
constexpr int SCAN_CHUNK = 1024;
constexpr int NBLK_SCAN = (N_NODES + SCAN_CHUNK - 1) / SCAN_CHUNK;   // 98

typedef float f32x4 __attribute__((ext_vector_type(4)));
typedef short short8 __attribute__((ext_vector_type(8)));

__device__ __forceinline__ ushort f2bf(float x) {            // fp32 -> bf16 RNE
    unsigned u = __float_as_uint(x);
    return (ushort)((u + 0x7fffu + ((u >> 16) & 1u)) >> 16);
}
__device__ __forceinline__ float bf2f(ushort h) {
    return __uint_as_float(((unsigned)h) << 16);
}

// ---------------- degree / norm ----------------
__global__ void k_deg(const int* __restrict__ dst, int E, int* __restrict__ deg) {
    int i = blockIdx.x * blockDim.x + threadIdx.x;
    if (i < E) atomicAdd(deg + dst[i], 1);
}

__global__ void k_norm(const int* __restrict__ deg, float* __restrict__ norm) {
    int i = blockIdx.x * blockDim.x + threadIdx.x;
    if (i < N_NODES) norm[i] = rsqrtf(fmaxf((float)deg[i], 1.0f));
}

// ---------------- 3-phase exclusive scan of deg -> offsets ----------------
__global__ __launch_bounds__(256) void k_scan1(const int* __restrict__ deg, int* __restrict__ part) {
    __shared__ int lds[256];
    int base = blockIdx.x * SCAN_CHUNK;
    int t = threadIdx.x;
    int s = 0;
    #pragma unroll
    for (int j = 0; j < 4; ++j) {
        int i = base + t * 4 + j;
        if (i < N_NODES) s += deg[i];
    }
    lds[t] = s; __syncthreads();
    for (int off = 128; off > 0; off >>= 1) {
        if (t < off) lds[t] += lds[t + off];
        __syncthreads();
    }
    if (t == 0) part[blockIdx.x] = lds[0];
}

__global__ void k_scan2(int* __restrict__ part) {
    if (threadIdx.x == 0 && blockIdx.x == 0) {
        int run = 0;
        for (int i = 0; i < NBLK_SCAN; ++i) { int v = part[i]; part[i] = run; run += v; }
    }
}

__global__ __launch_bounds__(256) void k_scan3(const int* __restrict__ deg, const int* __restrict__ part,
                                               int* __restrict__ offs, int* __restrict__ curs) {
    __shared__ int lds[256];
    int base = blockIdx.x * SCAN_CHUNK;
    int t = threadIdx.x;
    int v[4]; int s = 0;
    #pragma unroll
    for (int j = 0; j < 4; ++j) {
        int i = base + t * 4 + j;
        v[j] = (i < N_NODES) ? deg[i] : 0;
        s += v[j];
    }
    lds[t] = s; __syncthreads();
    for (int off = 1; off < 256; off <<= 1) {
        int x = (t >= off) ? lds[t - off] : 0;
        __syncthreads();
        lds[t] += x;
        __syncthreads();
    }
    int run = part[blockIdx.x] + lds[t] - s;
    #pragma unroll
    for (int j = 0; j < 4; ++j) {
        int i = base + t * 4 + j;
        if (i < N_NODES) { offs[i] = run; curs[i] = run; }
        run += v[j];
    }
}

// ---------------- bucket edges by dst ----------------
__global__ void k_bucket(const int* __restrict__ src, const int* __restrict__ dst, int E,
                         int* __restrict__ curs, int* __restrict__ esrc) {
    int i = blockIdx.x * blockDim.x + threadIdx.x;
    if (i < E) {
        int pos = atomicAdd(curs + dst[i], 1);
        esrc[pos] = src[i];
    }
}

// ---------------- gather: one wave per dst node ----------------
__global__ __launch_bounds__(256) void k_gather(const float* __restrict__ feat,
                                                const float* __restrict__ norm,
                                                const int* __restrict__ offs,
                                                const int* __restrict__ deg,
                                                const int* __restrict__ esrc,
                                                float* __restrict__ agg) {
    int gtid = blockIdx.x * blockDim.x + threadIdx.x;
    int node = gtid >> 6;
    int lane = gtid & 63;
    if (node >= N_NODES) return;
    int start = offs[node];
    int cnt   = deg[node];
    float2 acc = {0.f, 0.f};
    const float2* feat2 = (const float2*)feat;
    int j = 0;
    for (; j + 2 <= cnt; j += 2) {
        int s0 = esrc[start + j];
        int s1 = esrc[start + j + 1];
        float n0 = norm[s0], n1 = norm[s1];
        float2 v0 = feat2[(size_t)s0 * 64 + lane];
        float2 v1 = feat2[(size_t)s1 * 64 + lane];
        acc.x = fmaf(v0.x, n0, acc.x); acc.y = fmaf(v0.y, n0, acc.y);
        acc.x = fmaf(v1.x, n1, acc.x); acc.y = fmaf(v1.y, n1, acc.y);
    }
    if (j < cnt) {
        int s0 = esrc[start + j];
        float n0 = norm[s0];
        float2 v0 = feat2[(size_t)s0 * 64 + lane];
        acc.x = fmaf(v0.x, n0, acc.x); acc.y = fmaf(v0.y, n0, acc.y);
    }
    ((float2*)agg)[(size_t)node * 64 + lane] = acc;
}

// ---------------- W pack: fragment-order bf16 hi/lo ----------------
// pack[((ct*4+kt)*64 + l)*8 + i] = W[kt*32 + (l>>4)*8 + i][ct*16 + (l&15)]
__global__ void k_wpack(const float* __restrict__ W, ushort* __restrict__ whi,
                        ushort* __restrict__ wlo) {
    int p = blockIdx.x * blockDim.x + threadIdx.x;
    if (p >= 16384) return;
    int i  = p & 7;
    int l  = (p >> 3) & 63;
    int kt = (p >> 9) & 3;
    int ct = (p >> 11);
    int k = kt * 32 + (l >> 4) * 8 + i;
    int n = ct * 16 + (l & 15);
    float x = W[k * 128 + n];
    ushort h = f2bf(x);
    whi[p] = h;
    wlo[p] = f2bf(x - bf2f(h));
}

// ---------------- split-bf16 MFMA GEMM, in-place on io ----------------
__global__ __launch_bounds__(256) void k_gemm_mfma(float* __restrict__ io,
                                                   const ushort* __restrict__ whi,
                                                   const ushort* __restrict__ wlo,
                                                   const float* __restrict__ bias,
                                                   const float* __restrict__ norm) {
    __shared__ ushort sH[16384];   // 32 KB
    __shared__ ushort sL[16384];   // 32 KB
    {
        const short8* gh = (const short8*)whi;
        const short8* gl = (const short8*)wlo;
        short8* lh = (short8*)sH;
        short8* ll = (short8*)sL;
        for (int i = threadIdx.x; i < 2048; i += 256) { lh[i] = gh[i]; ll[i] = gl[i]; }
    }
    __syncthreads();

    const int lane = threadIdx.x & 63;
    const int wid  = threadIdx.x >> 6;
    const int rsub = lane & 15;        // A row within tile / output col within tile
    const int kgrp = lane >> 4;        // 0..3

    const short8* BH = (const short8*)sH;
    const short8* BL = (const short8*)sL;

    const int nstrips = N_NODES / 16;  // 6250
    for (int strip = blockIdx.x * 4 + wid; strip < nstrips; strip += gridDim.x * 4) {
        const int row0 = strip * 16;
        // A-frags: lane holds row (row0+rsub), k = kt*32 + kgrp*8 + (0..7); split fp32->hi+lo
        const float* arow = io + (size_t)(row0 + rsub) * D + kgrp * 8;
        short8 ahi[4], alo[4];
        #pragma unroll
        for (int kt = 0; kt < 4; ++kt) {
            f32x4 x0 = *(const f32x4*)(arow + kt * 32);
            f32x4 x1 = *(const f32x4*)(arow + kt * 32 + 4);
            short8 h, l;
            #pragma unroll
            for (int j = 0; j < 4; ++j) {
                ushort h0 = f2bf(x0[j]);
                h[j]     = (short)h0;  l[j]     = (short)f2bf(x0[j] - bf2f(h0));
                ushort h1 = f2bf(x1[j]);
                h[j + 4] = (short)h1;  l[j + 4] = (short)f2bf(x1[j] - bf2f(h1));
            }
            ahi[kt] = h; alo[kt] = l;
        }
        float nr[4];
        #pragma unroll
        for (int r = 0; r < 4; ++r) nr[r] = norm[row0 + kgrp * 4 + r];

        #pragma unroll
        for (int ct = 0; ct < 8; ++ct) {
            f32x4 acc = {0.f, 0.f, 0.f, 0.f};
            #pragma unroll
            for (int kt = 0; kt < 4; ++kt) {
                short8 bh = BH[(ct * 4 + kt) * 64 + lane];
                short8 bl = BL[(ct * 4 + kt) * 64 + lane];
                acc = __builtin_amdgcn_mfma_f32_16x16x32_bf16(ahi[kt], bh, acc, 0, 0, 0);
                acc = __builtin_amdgcn_mfma_f32_16x16x32_bf16(alo[kt], bh, acc, 0, 0, 0);
                acc = __builtin_amdgcn_mfma_f32_16x16x32_bf16(ahi[kt], bl, acc, 0, 0, 0);
            }
            // C/D: col = ct*16 + (lane&15), row = kgrp*4 + r   [m89 verified mapping]
            const float bc = bias[ct * 16 + rsub];
            float* ocol = io + (size_t)row0 * D + ct * 16 + rsub;
            #pragma unroll
            for (int r = 0; r < 4; ++r) {
                int row = kgrp * 4 + r;
                ocol[(size_t)row * D] = acc[r] * nr[r] + bc;
            }
        }
    }
}

// ---------------- fallback path (round 0) ----------------
__global__ void k_scatter(const float* __restrict__ feat, const int* __restrict__ src,
                          const int* __restrict__ dst, const float* __restrict__ norm,
                          int E, float* __restrict__ agg) {
    long long gtid = (long long)blockIdx.x * blockDim.x + threadIdx.x;
    int e    = (int)(gtid >> 6);
    int lane = (int)(gtid & 63);
    if (e >= E) return;
    int s = src[e];
    int t = dst[e];
    float ns = norm[s];
    float2 v = ((const float2*)(feat + (size_t)s * D))[lane];
    float* arow = agg + (size_t)t * D + lane * 2;
    atomicAdd(arow + 0, v.x * ns);
    atomicAdd(arow + 1, v.y * ns);
}

__global__ void k_deg_f(const int* __restrict__ dst, int E, float* __restrict__ deg) {
    int i = blockIdx.x * blockDim.x + threadIdx.x;
    if (i < E) atomicAdd(deg + dst[i], 1.0f);
}
__global__ void k_norm_f(float* __restrict__ dn) {
    int i = blockIdx.x * blockDim.x + threadIdx.x;
    if (i < N_NODES) dn[i] = rsqrtf(fmaxf(dn[i], 1.0f));
}

__global__ __launch_bounds__(256) void k_gemm(float* __restrict__ io,
                                              const float* __restrict__ W,
                                              const float* __restrict__ bias,
                                              const float* __restrict__ norm) {
    __shared__ float sW[D * D];
    __shared__ float srow[2][D];
    for (int i = threadIdx.x; i < D * D; i += 256) sW[i] = W[i];
    const int r = threadIdx.x >> 7;
    const int c = threadIdx.x & 127;
    const float bc = bias[c];
    const int npairs = N_NODES / 2;
    for (int rp = blockIdx.x; rp < npairs; rp += gridDim.x) {
        __syncthreads();
        const int row = rp * 2 + r;
        srow[r][c] = io[(size_t)row * D + c];
        __syncthreads();
        float acc = 0.f;
        #pragma unroll 8
        for (int k = 0; k < D; ++k)
            acc = fmaf(srow[r][k], sW[k * D + c], acc);
        io[(size_t)row * D + c] = acc * norm[row] + bc;
    }
}

extern "C" void kernel_launch(void* const* d_in, const int* in_sizes, int n_in,
                              void* d_out, int out_size, void* d_ws, size_t ws_size,
                              hipStream_t stream) {
    const float* feat   = (const float*)d_in[0];
    const float* weight = (const float*)d_in[1];
    const float* bias   = (const float*)d_in[2];
    const int*   src    = (const int*)d_in[3];
    const int*   dst    = (const int*)d_in[4];
    const int E = in_sizes[3];

    float* agg = (float*)d_out;

    // workspace layout
    float*  norm = (float*)d_ws;                 // N floats
    int*    deg  = (int*)(norm + N_NODES);       // N ints
    int*    offs = deg + N_NODES;                // N ints
    int*    curs = offs + N_NODES;               // N ints
    int*    part = curs + N_NODES;               // 128 ints
    int*    esrc = part + 128;                   // E ints
    ushort* whi  = (ushort*)(esrc + E);          // 16384 ushort
    ushort* wlo  = whi + 16384;                  // 16384 ushort
    size_t need = ((size_t)4 * N_NODES + 128 + (size_t)E) * 4 + 65536;

    if (ws_size >= need) {
        k_wpack<<<64, 256, 0, stream>>>(weight, whi, wlo);
        hipMemsetAsync(deg, 0, (size_t)N_NODES * sizeof(int), stream);
        k_deg<<<(E + 255) / 256, 256, 0, stream>>>(dst, E, deg);
        k_norm<<<(N_NODES + 255) / 256, 256, 0, stream>>>(deg, norm);
        k_scan1<<<NBLK_SCAN, 256, 0, stream>>>(deg, part);
        k_scan2<<<1, 64, 0, stream>>>(part);
        k_scan3<<<NBLK_SCAN, 256, 0, stream>>>(deg, part, offs, curs);
        k_bucket<<<(E + 255) / 256, 256, 0, stream>>>(src, dst, E, curs, esrc);
        long long gthreads = (long long)N_NODES * 64;
        k_gather<<<(int)((gthreads + 255) / 256), 256, 0, stream>>>(feat, norm, offs, deg, esrc, agg);
        k_gemm_mfma<<<1024, 256, 0, stream>>>(agg, whi, wlo, bias, norm);
    } else {
        hipMemsetAsync(d_out, 0, (size_t)N_NODES * D * sizeof(float), stream);
        hipMemsetAsync(norm, 0, (size_t)N_NODES * sizeof(float), stream);
        k_deg_f<<<(E + 255) / 256, 256, 0, stream>>>(dst, E, norm);
        k_norm_f<<<(N_NODES + 255) / 256, 256, 0, stream>>>(norm);
        long long sthreads = (long long)E * 64;
        k_scatter<<<(int)((sthreads + 255) / 256), 256, 0, stream>>>(feat, src, dst, norm, E, agg);
        k_gemm<<<4096, 256, 0, stream>>>(agg, weight, bias, norm);
    }
}

// Round 4
// 247.620 us; speedup vs baseline: 6.5181x; 1.4794x over previous
//
#include <hip/hip_runtime.h>

// GraphConv: deg/norm + CSR-by-dst + gather + split-bf16 MFMA GEMM.
// Round 3: (a) replace atomic k_deg/k_bucket (165us of scattered-line RMW traffic)
//              with a deterministic 2-level counting sort (LDS histograms, coalesced writes);
//          (b) gather reads bf16 feat (halves the 819MB random-read traffic).

constexpr int N_NODES = 100000;
constexpr int D = 128;
constexpr int SCAN_CHUNK = 1024;
constexpr int NBLK_SCAN = (N_NODES + SCAN_CHUNK - 1) / SCAN_CHUNK;   // 98
constexpr int NB = 256;                       // coarse buckets
constexpr int GROUP = (N_NODES + NB - 1) / NB; // 391 nodes per bucket
constexpr int CAP = 14336;                    // LDS esrc staging capacity (56KB)

typedef float f32x4 __attribute__((ext_vector_type(4)));
typedef short short8 __attribute__((ext_vector_type(8)));

__device__ __forceinline__ ushort f2bf(float x) {            // fp32 -> bf16 RNE
    unsigned u = __float_as_uint(x);
    return (ushort)((u + 0x7fffu + ((u >> 16) & 1u)) >> 16);
}
__device__ __forceinline__ float bf2f(ushort h) {
    return __uint_as_float(((unsigned)h) << 16);
}

// ---------------- pass 1: coarse partition (deterministic layout) ----------------
// Each of NB blocks owns a contiguous edge chunk; builds LDS 256-histogram of dst/GROUP.
__global__ __launch_bounds__(256) void p1_histo(const int* __restrict__ dst, int E,
                                                int* __restrict__ bhist) {
    __shared__ int h[NB];
    int t = threadIdx.x, blk = blockIdx.x;
    h[t] = 0; __syncthreads();
    int per = (E + NB - 1) / NB;
    int s = blk * per, e = min(E, s + per);
    for (int i = s + t; i < e; i += 256) atomicAdd(&h[dst[i] / GROUP], 1);
    __syncthreads();
    bhist[t * NB + blk] = h[t];          // bucket-major
}

// Single block: per-bucket exclusive scan over blocks, then scan over buckets.
__global__ __launch_bounds__(256) void p1_scan(int* __restrict__ bhist,
                                               int* __restrict__ bktBase, int E) {
    __shared__ int tot[NB];
    int b = threadIdx.x;
    int run = 0;
    for (int i = 0; i < NB; ++i) { int v = bhist[b * NB + i]; bhist[b * NB + i] = run; run += v; }
    tot[b] = run; __syncthreads();
    for (int off = 1; off < NB; off <<= 1) {
        int x = (b >= off) ? tot[b - off] : 0;
        __syncthreads();
        tot[b] += x;
        __syncthreads();
    }
    int base = tot[b] - run;             // exclusive prefix
    bktBase[b] = base;
    if (b == NB - 1) bktBase[NB] = tot[NB - 1];   // == E
    for (int i = 0; i < NB; ++i) bhist[b * NB + i] += base;
}

// Scatter packed (dloc<<17 | src) into coarse-bucket regions of `pairs`.
__global__ __launch_bounds__(256) void p1_scatter(const int* __restrict__ src,
                                                  const int* __restrict__ dst, int E,
                                                  const int* __restrict__ bhist,
                                                  int* __restrict__ pairs) {
    __shared__ int loff[NB];
    int t = threadIdx.x, blk = blockIdx.x;
    loff[t] = bhist[t * NB + blk]; __syncthreads();
    int per = (E + NB - 1) / NB;
    int s = blk * per, e = min(E, s + per);
    for (int i = s + t; i < e; i += 256) {
        int d = dst[i];
        int b = d / GROUP;
        int pos = atomicAdd(&loff[b], 1);
        pairs[pos] = ((d - b * GROUP) << 17) | src[i];
    }
}

// ---------------- pass 2: per-bucket fine histogram -> deg (no global atomics) ----------------
__global__ __launch_bounds__(256) void p2_deg(const int* __restrict__ pairs,
                                              const int* __restrict__ bktBase,
                                              int* __restrict__ deg) {
    __shared__ int h[GROUP];
    int t = threadIdx.x, b = blockIdx.x;
    int lo = b * GROUP;
    int cnt = min(GROUP, N_NODES - lo);
    for (int i = t; i < GROUP; i += 256) h[i] = 0;
    __syncthreads();
    int s0 = bktBase[b], s1 = bktBase[b + 1];
    for (int i = s0 + t; i < s1; i += 256) atomicAdd(&h[pairs[i] >> 17], 1);
    __syncthreads();
    for (int i = t; i < cnt; i += 256) deg[lo + i] = h[i];
}

// Per-bucket scatter of src into its contiguous esrc window, staged in LDS (coalesced write).
__global__ __launch_bounds__(256) void p2_scatter(const int* __restrict__ pairs,
                                                  const int* __restrict__ bktBase,
                                                  const int* __restrict__ offs, int E,
                                                  int* __restrict__ esrc) {
    __shared__ int loffs[GROUP];
    __shared__ int lcur[GROUP];
    __shared__ int sbuf[CAP];
    int t = threadIdx.x, b = blockIdx.x;
    int lo = b * GROUP;
    int cnt = min(GROUP, N_NODES - lo);
    int base = offs[lo];
    int end  = (lo + cnt < N_NODES) ? offs[lo + cnt] : E;
    int wsize = end - base;
    for (int i = t; i < cnt; i += 256) { loffs[i] = offs[lo + i] - base; lcur[i] = 0; }
    __syncthreads();
    int s0 = bktBase[b], s1 = bktBase[b + 1];
    bool fits = (wsize <= CAP);
    for (int i = s0 + t; i < s1; i += 256) {
        int p = pairs[i];
        int dl = p >> 17;
        int sv = p & 0x1FFFF;
        int pos = loffs[dl] + atomicAdd(&lcur[dl], 1);
        if (fits) sbuf[pos] = sv; else esrc[base + pos] = sv;
    }
    __syncthreads();
    if (fits)
        for (int i = t; i < wsize; i += 256) esrc[base + i] = sbuf[i];
}

// ---------------- norm / scan ----------------
__global__ void k_norm(const int* __restrict__ deg, float* __restrict__ norm) {
    int i = blockIdx.x * blockDim.x + threadIdx.x;
    if (i < N_NODES) norm[i] = rsqrtf(fmaxf((float)deg[i], 1.0f));
}

__global__ __launch_bounds__(256) void k_scan1(const int* __restrict__ deg, int* __restrict__ part) {
    __shared__ int lds[256];
    int base = blockIdx.x * SCAN_CHUNK;
    int t = threadIdx.x;
    int s = 0;
    #pragma unroll
    for (int j = 0; j < 4; ++j) {
        int i = base + t * 4 + j;
        if (i < N_NODES) s += deg[i];
    }
    lds[t] = s; __syncthreads();
    for (int off = 128; off > 0; off >>= 1) {
        if (t < off) lds[t] += lds[t + off];
        __syncthreads();
    }
    if (t == 0) part[blockIdx.x] = lds[0];
}

__global__ void k_scan2(int* __restrict__ part) {
    if (threadIdx.x == 0 && blockIdx.x == 0) {
        int run = 0;
        for (int i = 0; i < NBLK_SCAN; ++i) { int v = part[i]; part[i] = run; run += v; }
    }
}

__global__ __launch_bounds__(256) void k_scan3(const int* __restrict__ deg, const int* __restrict__ part,
                                               int* __restrict__ offs) {
    __shared__ int lds[256];
    int base = blockIdx.x * SCAN_CHUNK;
    int t = threadIdx.x;
    int v[4]; int s = 0;
    #pragma unroll
    for (int j = 0; j < 4; ++j) {
        int i = base + t * 4 + j;
        v[j] = (i < N_NODES) ? deg[i] : 0;
        s += v[j];
    }
    lds[t] = s; __syncthreads();
    for (int off = 1; off < 256; off <<= 1) {
        int x = (t >= off) ? lds[t - off] : 0;
        __syncthreads();
        lds[t] += x;
        __syncthreads();
    }
    int run = part[blockIdx.x] + lds[t] - s;
    #pragma unroll
    for (int j = 0; j < 4; ++j) {
        int i = base + t * 4 + j;
        if (i < N_NODES) offs[i] = run;
        run += v[j];
    }
}

// ---------------- feat -> bf16 ----------------
__global__ void k_featbf(const float* __restrict__ feat, unsigned* __restrict__ ft, int total) {
    int i = blockIdx.x * blockDim.x + threadIdx.x;   // one uint = 2 bf16 = 2 floats
    if (i < total) {
        float2 v = ((const float2*)feat)[i];
        ft[i] = (unsigned)f2bf(v.x) | ((unsigned)f2bf(v.y) << 16);
    }
}

// ---------------- gather (bf16 feat): one wave per dst node ----------------
__global__ __launch_bounds__(256) void k_gather_bf(const unsigned* __restrict__ ft,
                                                   const float* __restrict__ norm,
                                                   const int* __restrict__ offs,
                                                   const int* __restrict__ deg,
                                                   const int* __restrict__ esrc,
                                                   float* __restrict__ agg) {
    int gtid = blockIdx.x * blockDim.x + threadIdx.x;
    int node = gtid >> 6;
    int lane = gtid & 63;
    if (node >= N_NODES) return;
    int start = offs[node];
    int cnt   = deg[node];
    float2 acc = {0.f, 0.f};
    int j = 0;
    for (; j + 2 <= cnt; j += 2) {
        int s0 = esrc[start + j];
        int s1 = esrc[start + j + 1];
        float n0 = norm[s0], n1 = norm[s1];
        unsigned u0 = ft[(size_t)s0 * 64 + lane];
        unsigned u1 = ft[(size_t)s1 * 64 + lane];
        acc.x = fmaf(__uint_as_float(u0 << 16), n0, acc.x);
        acc.y = fmaf(__uint_as_float(u0 & 0xffff0000u), n0, acc.y);
        acc.x = fmaf(__uint_as_float(u1 << 16), n1, acc.x);
        acc.y = fmaf(__uint_as_float(u1 & 0xffff0000u), n1, acc.y);
    }
    if (j < cnt) {
        int s0 = esrc[start + j];
        float n0 = norm[s0];
        unsigned u0 = ft[(size_t)s0 * 64 + lane];
        acc.x = fmaf(__uint_as_float(u0 << 16), n0, acc.x);
        acc.y = fmaf(__uint_as_float(u0 & 0xffff0000u), n0, acc.y);
    }
    ((float2*)agg)[(size_t)node * 64 + lane] = acc;
}

// ---------------- gather (fp32 feat) fallback tier ----------------
__global__ __launch_bounds__(256) void k_gather(const float* __restrict__ feat,
                                                const float* __restrict__ norm,
                                                const int* __restrict__ offs,
                                                const int* __restrict__ deg,
                                                const int* __restrict__ esrc,
                                                float* __restrict__ agg) {
    int gtid = blockIdx.x * blockDim.x + threadIdx.x;
    int node = gtid >> 6;
    int lane = gtid & 63;
    if (node >= N_NODES) return;
    int start = offs[node];
    int cnt   = deg[node];
    float2 acc = {0.f, 0.f};
    const float2* feat2 = (const float2*)feat;
    int j = 0;
    for (; j + 2 <= cnt; j += 2) {
        int s0 = esrc[start + j];
        int s1 = esrc[start + j + 1];
        float n0 = norm[s0], n1 = norm[s1];
        float2 v0 = feat2[(size_t)s0 * 64 + lane];
        float2 v1 = feat2[(size_t)s1 * 64 + lane];
        acc.x = fmaf(v0.x, n0, acc.x); acc.y = fmaf(v0.y, n0, acc.y);
        acc.x = fmaf(v1.x, n1, acc.x); acc.y = fmaf(v1.y, n1, acc.y);
    }
    if (j < cnt) {
        int s0 = esrc[start + j];
        float n0 = norm[s0];
        float2 v0 = feat2[(size_t)s0 * 64 + lane];
        acc.x = fmaf(v0.x, n0, acc.x); acc.y = fmaf(v0.y, n0, acc.y);
    }
    ((float2*)agg)[(size_t)node * 64 + lane] = acc;
}

// ---------------- W pack: fragment-order bf16 hi/lo ----------------
__global__ void k_wpack(const float* __restrict__ W, ushort* __restrict__ whi,
                        ushort* __restrict__ wlo) {
    int p = blockIdx.x * blockDim.x + threadIdx.x;
    if (p >= 16384) return;
    int i  = p & 7;
    int l  = (p >> 3) & 63;
    int kt = (p >> 9) & 3;
    int ct = (p >> 11);
    int k = kt * 32 + (l >> 4) * 8 + i;
    int n = ct * 16 + (l & 15);
    float x = W[k * 128 + n];
    ushort h = f2bf(x);
    whi[p] = h;
    wlo[p] = f2bf(x - bf2f(h));
}

// ---------------- split-bf16 MFMA GEMM, in-place on io ----------------
__global__ __launch_bounds__(256) void k_gemm_mfma(float* __restrict__ io,
                                                   const ushort* __restrict__ whi,
                                                   const ushort* __restrict__ wlo,
                                                   const float* __restrict__ bias,
                                                   const float* __restrict__ norm) {
    __shared__ ushort sH[16384];
    __shared__ ushort sL[16384];
    {
        const short8* gh = (const short8*)whi;
        const short8* gl = (const short8*)wlo;
        short8* lh = (short8*)sH;
        short8* ll = (short8*)sL;
        for (int i = threadIdx.x; i < 2048; i += 256) { lh[i] = gh[i]; ll[i] = gl[i]; }
    }
    __syncthreads();

    const int lane = threadIdx.x & 63;
    const int wid  = threadIdx.x >> 6;
    const int rsub = lane & 15;
    const int kgrp = lane >> 4;

    const short8* BH = (const short8*)sH;
    const short8* BL = (const short8*)sL;

    const int nstrips = N_NODES / 16;
    for (int strip = blockIdx.x * 4 + wid; strip < nstrips; strip += gridDim.x * 4) {
        const int row0 = strip * 16;
        const float* arow = io + (size_t)(row0 + rsub) * D + kgrp * 8;
        short8 ahi[4], alo[4];
        #pragma unroll
        for (int kt = 0; kt < 4; ++kt) {
            f32x4 x0 = *(const f32x4*)(arow + kt * 32);
            f32x4 x1 = *(const f32x4*)(arow + kt * 32 + 4);
            short8 h, l;
            #pragma unroll
            for (int j = 0; j < 4; ++j) {
                ushort h0 = f2bf(x0[j]);
                h[j]     = (short)h0;  l[j]     = (short)f2bf(x0[j] - bf2f(h0));
                ushort h1 = f2bf(x1[j]);
                h[j + 4] = (short)h1;  l[j + 4] = (short)f2bf(x1[j] - bf2f(h1));
            }
            ahi[kt] = h; alo[kt] = l;
        }
        float nr[4];
        #pragma unroll
        for (int r = 0; r < 4; ++r) nr[r] = norm[row0 + kgrp * 4 + r];

        #pragma unroll
        for (int ct = 0; ct < 8; ++ct) {
            f32x4 acc = {0.f, 0.f, 0.f, 0.f};
            #pragma unroll
            for (int kt = 0; kt < 4; ++kt) {
                short8 bh = BH[(ct * 4 + kt) * 64 + lane];
                short8 bl = BL[(ct * 4 + kt) * 64 + lane];
                acc = __builtin_amdgcn_mfma_f32_16x16x32_bf16(ahi[kt], bh, acc, 0, 0, 0);
                acc = __builtin_amdgcn_mfma_f32_16x16x32_bf16(alo[kt], bh, acc, 0, 0, 0);
                acc = __builtin_amdgcn_mfma_f32_16x16x32_bf16(ahi[kt], bl, acc, 0, 0, 0);
            }
            const float bc = bias[ct * 16 + rsub];
            float* ocol = io + (size_t)row0 * D + ct * 16 + rsub;
            #pragma unroll
            for (int r = 0; r < 4; ++r) {
                int row = kgrp * 4 + r;
                ocol[(size_t)row * D] = acc[r] * nr[r] + bc;
            }
        }
    }
}

// ---------------- last-resort fallback (atomic scatter) ----------------
__global__ void k_scatter(const float* __restrict__ feat, const int* __restrict__ src,
                          const int* __restrict__ dst, const float* __restrict__ norm,
                          int E, float* __restrict__ agg) {
    long long gtid = (long long)blockIdx.x * blockDim.x + threadIdx.x;
    int e    = (int)(gtid >> 6);
    int lane = (int)(gtid & 63);
    if (e >= E) return;
    int s = src[e];
    int t = dst[e];
    float ns = norm[s];
    float2 v = ((const float2*)(feat + (size_t)s * D))[lane];
    float* arow = agg + (size_t)t * D + lane * 2;
    atomicAdd(arow + 0, v.x * ns);
    atomicAdd(arow + 1, v.y * ns);
}
__global__ void k_deg_f(const int* __restrict__ dst, int E, float* __restrict__ deg) {
    int i = blockIdx.x * blockDim.x + threadIdx.x;
    if (i < E) atomicAdd(deg + dst[i], 1.0f);
}
__global__ void k_norm_f(float* __restrict__ dn) {
    int i = blockIdx.x * blockDim.x + threadIdx.x;
    if (i < N_NODES) dn[i] = rsqrtf(fmaxf(dn[i], 1.0f));
}
__global__ __launch_bounds__(256) void k_gemm(float* __restrict__ io,
                                              const float* __restrict__ W,
                                              const float* __restrict__ bias,
                                              const float* __restrict__ norm) {
    __shared__ float sW[D * D];
    __shared__ float srow[2][D];
    for (int i = threadIdx.x; i < D * D; i += 256) sW[i] = W[i];
    const int r = threadIdx.x >> 7;
    const int c = threadIdx.x & 127;
    const float bc = bias[c];
    const int npairs = N_NODES / 2;
    for (int rp = blockIdx.x; rp < npairs; rp += gridDim.x) {
        __syncthreads();
        const int row = rp * 2 + r;
        srow[r][c] = io[(size_t)row * D + c];
        __syncthreads();
        float acc = 0.f;
        #pragma unroll 8
        for (int k = 0; k < D; ++k)
            acc = fmaf(srow[r][k], sW[k * D + c], acc);
        io[(size_t)row * D + c] = acc * norm[row] + bc;
    }
}

extern "C" void kernel_launch(void* const* d_in, const int* in_sizes, int n_in,
                              void* d_out, int out_size, void* d_ws, size_t ws_size,
                              hipStream_t stream) {
    const float* feat   = (const float*)d_in[0];
    const float* weight = (const float*)d_in[1];
    const float* bias   = (const float*)d_in[2];
    const int*   src    = (const int*)d_in[3];
    const int*   dst    = (const int*)d_in[4];
    const int E = in_sizes[3];

    float* agg = (float*)d_out;
    int*   pairs = (int*)d_out;    // d_out doubles as pairs scratch (consumed before gather)

    // workspace layout
    float*    norm    = (float*)d_ws;              // N
    int*      deg     = (int*)(norm + N_NODES);    // N
    int*      offs    = deg + N_NODES;             // N
    int*      part    = offs + N_NODES;            // 128
    int*      bhist   = part + 128;                // 256*256
    int*      bktBase = bhist + NB * NB;           // 257
    int*      esrc    = bktBase + NB + 1;          // E
    ushort*   whi     = (ushort*)(esrc + E);       // 16384
    ushort*   wlo     = whi + 16384;               // 16384
    unsigned* ft      = (unsigned*)(wlo + 16384);  // N*64 uints (bf16x2)  [tier A only]

    size_t needB = ((size_t)3 * N_NODES + 128 + (size_t)NB * NB + NB + 1 + (size_t)E) * 4 + 65536;
    size_t needA = needB + (size_t)N_NODES * 64 * 4;

    if (ws_size >= needB) {
        k_wpack<<<64, 256, 0, stream>>>(weight, whi, wlo);
        // two-level counting sort (no global atomics, coalesced writes)
        p1_histo<<<NB, 256, 0, stream>>>(dst, E, bhist);
        p1_scan<<<1, NB, 0, stream>>>(bhist, bktBase, E);
        p1_scatter<<<NB, 256, 0, stream>>>(src, dst, E, bhist, pairs);
        p2_deg<<<NB, 256, 0, stream>>>(pairs, bktBase, deg);
        k_norm<<<(N_NODES + 255) / 256, 256, 0, stream>>>(deg, norm);
        k_scan1<<<NBLK_SCAN, 256, 0, stream>>>(deg, part);
        k_scan2<<<1, 64, 0, stream>>>(part);
        k_scan3<<<NBLK_SCAN, 256, 0, stream>>>(deg, part, offs);
        p2_scatter<<<NB, 256, 0, stream>>>(pairs, bktBase, offs, E, esrc);

        long long gthreads = (long long)N_NODES * 64;
        int gblocks = (int)((gthreads + 255) / 256);
        if (ws_size >= needA) {
            k_featbf<<<(N_NODES * 64 + 255) / 256, 256, 0, stream>>>(feat, ft, N_NODES * 64);
            k_gather_bf<<<gblocks, 256, 0, stream>>>(ft, norm, offs, deg, esrc, agg);
        } else {
            k_gather<<<gblocks, 256, 0, stream>>>(feat, norm, offs, deg, esrc, agg);
        }
        k_gemm_mfma<<<1024, 256, 0, stream>>>(agg, whi, wlo, bias, norm);
    } else {
        // last-resort: atomic scatter path
        hipMemsetAsync(d_out, 0, (size_t)N_NODES * D * sizeof(float), stream);
        hipMemsetAsync(norm, 0, (size_t)N_NODES * sizeof(float), stream);
        k_deg_f<<<(E + 255) / 256, 256, 0, stream>>>(dst, E, norm);
        k_norm_f<<<(N_NODES + 255) / 256, 256, 0, stream>>>(norm);
        long long sthreads = (long long)E * 64;
        k_scatter<<<(int)((sthreads + 255) / 256), 256, 0, stream>>>(feat, src, dst, norm, E, agg);
        k_gemm<<<4096, 256, 0, stream>>>(agg, weight, bias, norm);
    }
}

// Round 5
// 204.341 us; speedup vs baseline: 7.8986x; 1.2118x over previous
//
#include <hip/hip_runtime.h>

// GraphConv: counting-sort CSR + normed-bf16 gather (4 rows/wave) + bf16-A MFMA GEMM.
// Round 4: (a) gather processes 4 edges per wave with uint4 (16B/lane) loads and
//              norm folded into the bf16 feat table -> 4x fewer load instructions;
//          (b) agg stored bf16 (tier A2): GEMM reads half the bytes, 2 MFMAs/tile, no A-split.

constexpr int N_NODES = 100000;
constexpr int D = 128;
constexpr int SCAN_CHUNK = 1024;
constexpr int NBLK_SCAN = (N_NODES + SCAN_CHUNK - 1) / SCAN_CHUNK;   // 98
constexpr int NB = 256;                        // coarse buckets
constexpr int GROUP = (N_NODES + NB - 1) / NB; // 391 nodes per bucket
constexpr int CAP = 14336;                     // LDS esrc staging capacity (56KB)

typedef float f32x4 __attribute__((ext_vector_type(4)));
typedef short short8 __attribute__((ext_vector_type(8)));
typedef unsigned uint4v __attribute__((ext_vector_type(4)));

__device__ __forceinline__ ushort f2bf(float x) {            // fp32 -> bf16 RNE
    unsigned u = __float_as_uint(x);
    return (ushort)((u + 0x7fffu + ((u >> 16) & 1u)) >> 16);
}
__device__ __forceinline__ float bf2f(ushort h) {
    return __uint_as_float(((unsigned)h) << 16);
}

// ---------------- pass 1: coarse partition ----------------
__global__ __launch_bounds__(256) void p1_histo(const int* __restrict__ dst, int E,
                                                int* __restrict__ bhist) {
    __shared__ int h[NB];
    int t = threadIdx.x, blk = blockIdx.x;
    h[t] = 0; __syncthreads();
    int per = (E + NB - 1) / NB;
    int s = blk * per, e = min(E, s + per);
    for (int i = s + t; i < e; i += 256) atomicAdd(&h[dst[i] / GROUP], 1);
    __syncthreads();
    bhist[t * NB + blk] = h[t];          // bucket-major
}

__global__ __launch_bounds__(256) void p1_scan(int* __restrict__ bhist,
                                               int* __restrict__ bktBase, int E) {
    __shared__ int tot[NB];
    int b = threadIdx.x;
    int run = 0;
    for (int i = 0; i < NB; ++i) { int v = bhist[b * NB + i]; bhist[b * NB + i] = run; run += v; }
    tot[b] = run; __syncthreads();
    for (int off = 1; off < NB; off <<= 1) {
        int x = (b >= off) ? tot[b - off] : 0;
        __syncthreads();
        tot[b] += x;
        __syncthreads();
    }
    int base = tot[b] - run;
    bktBase[b] = base;
    if (b == NB - 1) bktBase[NB] = tot[NB - 1];
    for (int i = 0; i < NB; ++i) bhist[b * NB + i] += base;
}

__global__ __launch_bounds__(256) void p1_scatter(const int* __restrict__ src,
                                                  const int* __restrict__ dst, int E,
                                                  const int* __restrict__ bhist,
                                                  int* __restrict__ pairs) {
    __shared__ int loff[NB];
    int t = threadIdx.x, blk = blockIdx.x;
    loff[t] = bhist[t * NB + blk]; __syncthreads();
    int per = (E + NB - 1) / NB;
    int s = blk * per, e = min(E, s + per);
    for (int i = s + t; i < e; i += 256) {
        int d = dst[i];
        int b = d / GROUP;
        int pos = atomicAdd(&loff[b], 1);
        pairs[pos] = ((d - b * GROUP) << 17) | src[i];
    }
}

// ---------------- pass 2 ----------------
__global__ __launch_bounds__(256) void p2_deg(const int* __restrict__ pairs,
                                              const int* __restrict__ bktBase,
                                              int* __restrict__ deg) {
    __shared__ int h[GROUP];
    int t = threadIdx.x, b = blockIdx.x;
    int lo = b * GROUP;
    int cnt = min(GROUP, N_NODES - lo);
    for (int i = t; i < GROUP; i += 256) h[i] = 0;
    __syncthreads();
    int s0 = bktBase[b], s1 = bktBase[b + 1];
    for (int i = s0 + t; i < s1; i += 256) atomicAdd(&h[pairs[i] >> 17], 1);
    __syncthreads();
    for (int i = t; i < cnt; i += 256) deg[lo + i] = h[i];
}

__global__ __launch_bounds__(256) void p2_scatter(const int* __restrict__ pairs,
                                                  const int* __restrict__ bktBase,
                                                  const int* __restrict__ offs, int E,
                                                  int* __restrict__ esrc) {
    __shared__ int loffs[GROUP];
    __shared__ int lcur[GROUP];
    __shared__ int sbuf[CAP];
    int t = threadIdx.x, b = blockIdx.x;
    int lo = b * GROUP;
    int cnt = min(GROUP, N_NODES - lo);
    int base = offs[lo];
    int end  = (lo + cnt < N_NODES) ? offs[lo + cnt] : E;
    int wsize = end - base;
    for (int i = t; i < cnt; i += 256) { loffs[i] = offs[lo + i] - base; lcur[i] = 0; }
    __syncthreads();
    int s0 = bktBase[b], s1 = bktBase[b + 1];
    bool fits = (wsize <= CAP);
    for (int i = s0 + t; i < s1; i += 256) {
        int p = pairs[i];
        int dl = p >> 17;
        int sv = p & 0x1FFFF;
        int pos = loffs[dl] + atomicAdd(&lcur[dl], 1);
        if (fits) sbuf[pos] = sv; else esrc[base + pos] = sv;
    }
    __syncthreads();
    if (fits)
        for (int i = t; i < wsize; i += 256) esrc[base + i] = sbuf[i];
}

// ---------------- norm / scan ----------------
__global__ void k_norm(const int* __restrict__ deg, float* __restrict__ norm) {
    int i = blockIdx.x * blockDim.x + threadIdx.x;
    if (i < N_NODES) norm[i] = rsqrtf(fmaxf((float)deg[i], 1.0f));
}

__global__ __launch_bounds__(256) void k_scan1(const int* __restrict__ deg, int* __restrict__ part) {
    __shared__ int lds[256];
    int base = blockIdx.x * SCAN_CHUNK;
    int t = threadIdx.x;
    int s = 0;
    #pragma unroll
    for (int j = 0; j < 4; ++j) {
        int i = base + t * 4 + j;
        if (i < N_NODES) s += deg[i];
    }
    lds[t] = s; __syncthreads();
    for (int off = 128; off > 0; off >>= 1) {
        if (t < off) lds[t] += lds[t + off];
        __syncthreads();
    }
    if (t == 0) part[blockIdx.x] = lds[0];
}

__global__ void k_scan2(int* __restrict__ part) {
    if (threadIdx.x == 0 && blockIdx.x == 0) {
        int run = 0;
        for (int i = 0; i < NBLK_SCAN; ++i) { int v = part[i]; part[i] = run; run += v; }
    }
}

__global__ __launch_bounds__(256) void k_scan3(const int* __restrict__ deg, const int* __restrict__ part,
                                               int* __restrict__ offs) {
    __shared__ int lds[256];
    int base = blockIdx.x * SCAN_CHUNK;
    int t = threadIdx.x;
    int v[4]; int s = 0;
    #pragma unroll
    for (int j = 0; j < 4; ++j) {
        int i = base + t * 4 + j;
        v[j] = (i < N_NODES) ? deg[i] : 0;
        s += v[j];
    }
    lds[t] = s; __syncthreads();
    for (int off = 1; off < 256; off <<= 1) {
        int x = (t >= off) ? lds[t - off] : 0;
        __syncthreads();
        lds[t] += x;
        __syncthreads();
    }
    int run = part[blockIdx.x] + lds[t] - s;
    #pragma unroll
    for (int j = 0; j < 4; ++j) {
        int i = base + t * 4 + j;
        if (i < N_NODES) offs[i] = run;
        run += v[j];
    }
}

// ---------------- feat*norm -> bf16 table ----------------
__global__ void k_featbf(const float* __restrict__ feat, const float* __restrict__ norm,
                         unsigned* __restrict__ ft, int total) {
    int i = blockIdx.x * blockDim.x + threadIdx.x;   // one uint = 2 bf16 = 2 floats
    if (i < total) {
        float w = norm[i >> 6];
        float2 v = ((const float2*)feat)[i];
        ft[i] = (unsigned)f2bf(v.x * w) | ((unsigned)f2bf(v.y * w) << 16);
    }
}

// ---------------- gather: 4 edges per wave, 16B/lane loads ----------------
template<bool OUT_BF>
__global__ __launch_bounds__(256) void k_gather4(const unsigned* __restrict__ ft,
                                                 const int* __restrict__ offs,
                                                 const int* __restrict__ deg,
                                                 const int* __restrict__ esrc,
                                                 void* __restrict__ out) {
    int gtid = blockIdx.x * blockDim.x + threadIdx.x;
    int node = gtid >> 6;
    if (node >= N_NODES) return;
    int lane = gtid & 63;
    int g  = lane >> 4;       // edge subgroup 0..3
    int sl = lane & 15;       // 16 lanes x uint4 = 256B row
    int start = offs[node];
    int cnt   = deg[node];
    int last  = start + cnt - 1;
    float acc[8] = {0.f, 0.f, 0.f, 0.f, 0.f, 0.f, 0.f, 0.f};
    const uint4v* ftv = (const uint4v*)ft;
    for (int j = 0; j < cnt; j += 4) {
        int idx = start + j + g;
        int s = esrc[min(idx, last)];
        float w = (j + g < cnt) ? 1.0f : 0.0f;        // norm pre-folded into ft
        uint4v u = ftv[(size_t)s * 16 + sl];
        #pragma unroll
        for (int q = 0; q < 4; ++q) {
            unsigned uu = u[q];
            acc[q * 2]     = fmaf(__uint_as_float(uu << 16),          w, acc[q * 2]);
            acc[q * 2 + 1] = fmaf(__uint_as_float(uu & 0xffff0000u),  w, acc[q * 2 + 1]);
        }
    }
    #pragma unroll
    for (int q = 0; q < 8; ++q) {
        acc[q] += __shfl_xor(acc[q], 16, 64);
        acc[q] += __shfl_xor(acc[q], 32, 64);
    }
    if (OUT_BF) {
        if (g == 0) {
            uint4v o;
            #pragma unroll
            for (int q = 0; q < 4; ++q)
                o[q] = (unsigned)f2bf(acc[q * 2]) | ((unsigned)f2bf(acc[q * 2 + 1]) << 16);
            ((uint4v*)out)[(size_t)node * 16 + sl] = o;
        }
    } else {
        // lane (g,sl) writes columns sl*8 + g*2, +1
        float2 o = {acc[g * 2], acc[g * 2 + 1]};
        ((float2*)out)[(size_t)node * 64 + sl * 8 / 2 * 1 + (sl * 8 + g * 2) / 2 - (sl * 8) / 2 + sl * 4 + g] = o;
    }
}
// note: fp32 write index simplifies to node*64 + sl*4 + g   (float2 units)

// ---------------- gather (fp32 feat) fallback tier ----------------
__global__ __launch_bounds__(256) void k_gather(const float* __restrict__ feat,
                                                const float* __restrict__ norm,
                                                const int* __restrict__ offs,
                                                const int* __restrict__ deg,
                                                const int* __restrict__ esrc,
                                                float* __restrict__ agg) {
    int gtid = blockIdx.x * blockDim.x + threadIdx.x;
    int node = gtid >> 6;
    int lane = gtid & 63;
    if (node >= N_NODES) return;
    int start = offs[node];
    int cnt   = deg[node];
    float2 acc = {0.f, 0.f};
    const float2* feat2 = (const float2*)feat;
    int j = 0;
    for (; j + 2 <= cnt; j += 2) {
        int s0 = esrc[start + j];
        int s1 = esrc[start + j + 1];
        float n0 = norm[s0], n1 = norm[s1];
        float2 v0 = feat2[(size_t)s0 * 64 + lane];
        float2 v1 = feat2[(size_t)s1 * 64 + lane];
        acc.x = fmaf(v0.x, n0, acc.x); acc.y = fmaf(v0.y, n0, acc.y);
        acc.x = fmaf(v1.x, n1, acc.x); acc.y = fmaf(v1.y, n1, acc.y);
    }
    if (j < cnt) {
        int s0 = esrc[start + j];
        float n0 = norm[s0];
        float2 v0 = feat2[(size_t)s0 * 64 + lane];
        acc.x = fmaf(v0.x, n0, acc.x); acc.y = fmaf(v0.y, n0, acc.y);
    }
    ((float2*)agg)[(size_t)node * 64 + lane] = acc;
}

// ---------------- W pack: fragment-order bf16 hi/lo ----------------
__global__ void k_wpack(const float* __restrict__ W, ushort* __restrict__ whi,
                        ushort* __restrict__ wlo) {
    int p = blockIdx.x * blockDim.x + threadIdx.x;
    if (p >= 16384) return;
    int i  = p & 7;
    int l  = (p >> 3) & 63;
    int kt = (p >> 9) & 3;
    int ct = (p >> 11);
    int k = kt * 32 + (l >> 4) * 8 + i;
    int n = ct * 16 + (l & 15);
    float x = W[k * 128 + n];
    ushort h = f2bf(x);
    whi[p] = h;
    wlo[p] = f2bf(x - bf2f(h));
}

// ---------------- GEMM, A = bf16 agg (tier A2): out = aggbf @ (Whi+Wlo) * norm + bias ----------------
__global__ __launch_bounds__(256) void k_gemm_bf(const ushort* __restrict__ aggbf,
                                                 const ushort* __restrict__ whi,
                                                 const ushort* __restrict__ wlo,
                                                 const float* __restrict__ bias,
                                                 const float* __restrict__ norm,
                                                 float* __restrict__ out) {
    __shared__ ushort sH[16384];
    __shared__ ushort sL[16384];
    {
        const short8* gh = (const short8*)whi;
        const short8* gl = (const short8*)wlo;
        short8* lh = (short8*)sH;
        short8* ll = (short8*)sL;
        for (int i = threadIdx.x; i < 2048; i += 256) { lh[i] = gh[i]; ll[i] = gl[i]; }
    }
    __syncthreads();

    const int lane = threadIdx.x & 63;
    const int wid  = threadIdx.x >> 6;
    const int rsub = lane & 15;
    const int kgrp = lane >> 4;

    const short8* BH = (const short8*)sH;
    const short8* BL = (const short8*)sL;

    const int nstrips = N_NODES / 16;
    for (int strip = blockIdx.x * 4 + wid; strip < nstrips; strip += gridDim.x * 4) {
        const int row0 = strip * 16;
        const ushort* arow = aggbf + (size_t)(row0 + rsub) * D + kgrp * 8;
        short8 a[4];
        #pragma unroll
        for (int kt = 0; kt < 4; ++kt) a[kt] = *(const short8*)(arow + kt * 32);
        float nr[4];
        #pragma unroll
        for (int r = 0; r < 4; ++r) nr[r] = norm[row0 + kgrp * 4 + r];

        #pragma unroll
        for (int ct = 0; ct < 8; ++ct) {
            f32x4 acc = {0.f, 0.f, 0.f, 0.f};
            #pragma unroll
            for (int kt = 0; kt < 4; ++kt) {
                acc = __builtin_amdgcn_mfma_f32_16x16x32_bf16(a[kt], BH[(ct * 4 + kt) * 64 + lane], acc, 0, 0, 0);
                acc = __builtin_amdgcn_mfma_f32_16x16x32_bf16(a[kt], BL[(ct * 4 + kt) * 64 + lane], acc, 0, 0, 0);
            }
            const float bc = bias[ct * 16 + rsub];
            float* ocol = out + (size_t)row0 * D + ct * 16 + rsub;
            #pragma unroll
            for (int r = 0; r < 4; ++r) {
                int row = kgrp * 4 + r;
                ocol[(size_t)row * D] = acc[r] * nr[r] + bc;
            }
        }
    }
}

// ---------------- GEMM, A = fp32 agg in-place (tier A/B): split-bf16 A ----------------
__global__ __launch_bounds__(256) void k_gemm_mfma(float* __restrict__ io,
                                                   const ushort* __restrict__ whi,
                                                   const ushort* __restrict__ wlo,
                                                   const float* __restrict__ bias,
                                                   const float* __restrict__ norm) {
    __shared__ ushort sH[16384];
    __shared__ ushort sL[16384];
    {
        const short8* gh = (const short8*)whi;
        const short8* gl = (const short8*)wlo;
        short8* lh = (short8*)sH;
        short8* ll = (short8*)sL;
        for (int i = threadIdx.x; i < 2048; i += 256) { lh[i] = gh[i]; ll[i] = gl[i]; }
    }
    __syncthreads();

    const int lane = threadIdx.x & 63;
    const int wid  = threadIdx.x >> 6;
    const int rsub = lane & 15;
    const int kgrp = lane >> 4;

    const short8* BH = (const short8*)sH;
    const short8* BL = (const short8*)sL;

    const int nstrips = N_NODES / 16;
    for (int strip = blockIdx.x * 4 + wid; strip < nstrips; strip += gridDim.x * 4) {
        const int row0 = strip * 16;
        const float* arow = io + (size_t)(row0 + rsub) * D + kgrp * 8;
        short8 ahi[4], alo[4];
        #pragma unroll
        for (int kt = 0; kt < 4; ++kt) {
            f32x4 x0 = *(const f32x4*)(arow + kt * 32);
            f32x4 x1 = *(const f32x4*)(arow + kt * 32 + 4);
            short8 h, l;
            #pragma unroll
            for (int j = 0; j < 4; ++j) {
                ushort h0 = f2bf(x0[j]);
                h[j]     = (short)h0;  l[j]     = (short)f2bf(x0[j] - bf2f(h0));
                ushort h1 = f2bf(x1[j]);
                h[j + 4] = (short)h1;  l[j + 4] = (short)f2bf(x1[j] - bf2f(h1));
            }
            ahi[kt] = h; alo[kt] = l;
        }
        float nr[4];
        #pragma unroll
        for (int r = 0; r < 4; ++r) nr[r] = norm[row0 + kgrp * 4 + r];

        #pragma unroll
        for (int ct = 0; ct < 8; ++ct) {
            f32x4 acc = {0.f, 0.f, 0.f, 0.f};
            #pragma unroll
            for (int kt = 0; kt < 4; ++kt) {
                short8 bh = BH[(ct * 4 + kt) * 64 + lane];
                short8 bl = BL[(ct * 4 + kt) * 64 + lane];
                acc = __builtin_amdgcn_mfma_f32_16x16x32_bf16(ahi[kt], bh, acc, 0, 0, 0);
                acc = __builtin_amdgcn_mfma_f32_16x16x32_bf16(alo[kt], bh, acc, 0, 0, 0);
                acc = __builtin_amdgcn_mfma_f32_16x16x32_bf16(ahi[kt], bl, acc, 0, 0, 0);
            }
            const float bc = bias[ct * 16 + rsub];
            float* ocol = io + (size_t)row0 * D + ct * 16 + rsub;
            #pragma unroll
            for (int r = 0; r < 4; ++r) {
                int row = kgrp * 4 + r;
                ocol[(size_t)row * D] = acc[r] * nr[r] + bc;
            }
        }
    }
}

// ---------------- last-resort fallback (atomic scatter) ----------------
__global__ void k_scatter(const float* __restrict__ feat, const int* __restrict__ src,
                          const int* __restrict__ dst, const float* __restrict__ norm,
                          int E, float* __restrict__ agg) {
    long long gtid = (long long)blockIdx.x * blockDim.x + threadIdx.x;
    int e    = (int)(gtid >> 6);
    int lane = (int)(gtid & 63);
    if (e >= E) return;
    int s = src[e];
    int t = dst[e];
    float ns = norm[s];
    float2 v = ((const float2*)(feat + (size_t)s * D))[lane];
    float* arow = agg + (size_t)t * D + lane * 2;
    atomicAdd(arow + 0, v.x * ns);
    atomicAdd(arow + 1, v.y * ns);
}
__global__ void k_deg_f(const int* __restrict__ dst, int E, float* __restrict__ deg) {
    int i = blockIdx.x * blockDim.x + threadIdx.x;
    if (i < E) atomicAdd(deg + dst[i], 1.0f);
}
__global__ void k_norm_f(float* __restrict__ dn) {
    int i = blockIdx.x * blockDim.x + threadIdx.x;
    if (i < N_NODES) dn[i] = rsqrtf(fmaxf(dn[i], 1.0f));
}
__global__ __launch_bounds__(256) void k_gemm(float* __restrict__ io,
                                              const float* __restrict__ W,
                                              const float* __restrict__ bias,
                                              const float* __restrict__ norm) {
    __shared__ float sW[D * D];
    __shared__ float srow[2][D];
    for (int i = threadIdx.x; i < D * D; i += 256) sW[i] = W[i];
    const int r = threadIdx.x >> 7;
    const int c = threadIdx.x & 127;
    const float bc = bias[c];
    const int npairs = N_NODES / 2;
    for (int rp = blockIdx.x; rp < npairs; rp += gridDim.x) {
        __syncthreads();
        const int row = rp * 2 + r;
        srow[r][c] = io[(size_t)row * D + c];
        __syncthreads();
        float acc = 0.f;
        #pragma unroll 8
        for (int k = 0; k < D; ++k)
            acc = fmaf(srow[r][k], sW[k * D + c], acc);
        io[(size_t)row * D + c] = acc * norm[row] + bc;
    }
}

extern "C" void kernel_launch(void* const* d_in, const int* in_sizes, int n_in,
                              void* d_out, int out_size, void* d_ws, size_t ws_size,
                              hipStream_t stream) {
    const float* feat   = (const float*)d_in[0];
    const float* weight = (const float*)d_in[1];
    const float* bias   = (const float*)d_in[2];
    const int*   src    = (const int*)d_in[3];
    const int*   dst    = (const int*)d_in[4];
    const int E = in_sizes[3];

    float* agg   = (float*)d_out;
    int*   pairs = (int*)d_out;    // d_out doubles as pairs scratch (dead before agg is written)

    // ---- workspace allocator (64B aligned) ----
    uintptr_t cur = (uintptr_t)d_ws;
    uintptr_t wsend = cur + ws_size;
    auto take = [&](size_t bytes) -> void* {
        uintptr_t r = (cur + 63) & ~(uintptr_t)63;
        cur = r + bytes;
        return (void*)r;
    };

    size_t S_ft   = (size_t)N_NODES * 64 * 4;    // 25.6 MB
    size_t S_agg  = (size_t)N_NODES * D * 2;     // 25.6 MB
    size_t S_small = (size_t)(3 * N_NODES + 128 + NB * NB + NB + 1 + E) * 4 + 65536 + 16 * 64;
    size_t needB  = S_small;
    size_t needA  = S_small + S_ft + 64;
    size_t needA2 = needA + S_agg + 64;

    bool tierA2 = ws_size >= needA2;
    bool tierA  = ws_size >= needA;
    bool tierB  = ws_size >= needB;

    unsigned* ft    = (tierA || tierA2) ? (unsigned*)take(S_ft) : nullptr;
    ushort*   aggbf = tierA2 ? (ushort*)take(S_agg) : nullptr;
    float*    norm    = (float*)take((size_t)N_NODES * 4);
    int*      deg     = (int*)take((size_t)N_NODES * 4);
    int*      offs    = (int*)take((size_t)N_NODES * 4);
    int*      part    = (int*)take(128 * 4);
    int*      bhist   = (int*)take((size_t)NB * NB * 4);
    int*      bktBase = (int*)take((size_t)(NB + 1) * 4);
    int*      esrc    = (int*)take((size_t)E * 4);
    ushort*   whi     = (ushort*)take(16384 * 2);
    ushort*   wlo     = (ushort*)take(16384 * 2);
    (void)wsend;

    if (tierB) {
        k_wpack<<<64, 256, 0, stream>>>(weight, whi, wlo);
        // deterministic two-level counting sort
        p1_histo<<<NB, 256, 0, stream>>>(dst, E, bhist);
        p1_scan<<<1, NB, 0, stream>>>(bhist, bktBase, E);
        p1_scatter<<<NB, 256, 0, stream>>>(src, dst, E, bhist, pairs);
        p2_deg<<<NB, 256, 0, stream>>>(pairs, bktBase, deg);
        k_norm<<<(N_NODES + 255) / 256, 256, 0, stream>>>(deg, norm);
        k_scan1<<<NBLK_SCAN, 256, 0, stream>>>(deg, part);
        k_scan2<<<1, 64, 0, stream>>>(part);
        k_scan3<<<NBLK_SCAN, 256, 0, stream>>>(deg, part, offs);
        p2_scatter<<<NB, 256, 0, stream>>>(pairs, bktBase, offs, E, esrc);

        long long gthreads = (long long)N_NODES * 64;
        int gblocks = (int)((gthreads + 255) / 256);
        if (tierA || tierA2) {
            k_featbf<<<(N_NODES * 64 + 255) / 256, 256, 0, stream>>>(feat, norm, ft, N_NODES * 64);
            if (tierA2) {
                k_gather4<true><<<gblocks, 256, 0, stream>>>(ft, offs, deg, esrc, aggbf);
                k_gemm_bf<<<1024, 256, 0, stream>>>(aggbf, whi, wlo, bias, norm, (float*)d_out);
            } else {
                k_gather4<false><<<gblocks, 256, 0, stream>>>(ft, offs, deg, esrc, agg);
                k_gemm_mfma<<<1024, 256, 0, stream>>>(agg, whi, wlo, bias, norm);
            }
        } else {
            k_gather<<<gblocks, 256, 0, stream>>>(feat, norm, offs, deg, esrc, agg);
            k_gemm_mfma<<<1024, 256, 0, stream>>>(agg, whi, wlo, bias, norm);
        }
    } else {
        // last-resort: atomic scatter path
        hipMemsetAsync(d_out, 0, (size_t)N_NODES * D * sizeof(float), stream);
        hipMemsetAsync(norm, 0, (size_t)N_NODES * sizeof(float), stream);
        k_deg_f<<<(E + 255) / 256, 256, 0, stream>>>(dst, E, (float*)norm);
        k_norm_f<<<(N_NODES + 255) / 256, 256, 0, stream>>>((float*)norm);
        long long sthreads = (long long)E * 64;
        k_scatter<<<(int)((sthreads + 255) / 256), 256, 0, stream>>>(feat, src, dst, norm, E, agg);
        k_gemm<<<4096, 256, 0, stream>>>(agg, weight, bias, norm);
    }
}

// Round 6
// 160.698 us; speedup vs baseline: 10.0437x; 1.2716x over previous
//
#include <hip/hip_runtime.h>

// GraphConv: counting-sort CSR + normed-bf16 gather (4 rows/wave) + bf16-A MFMA GEMM.
// Round 5: de-serialize the sort pipeline.
//   - p1_scan (single-block serial, ~20us) -> p1_scanrow (256 parallel row scans) + p1_scantot
//   - k_scan1/2/3 + k_norm (4 launches incl. 1-thread serial scan) -> fused into p2_degoffs:
//     offs[node] = bktBase[bucket] + in-bucket prefix of the fine histogram.

constexpr int N_NODES = 100000;
constexpr int D = 128;
constexpr int NB = 256;                        // coarse buckets
constexpr int GROUP = (N_NODES + NB - 1) / NB; // 391 nodes per bucket
constexpr int CAP = 14336;                     // LDS esrc staging capacity (56KB)

typedef float f32x4 __attribute__((ext_vector_type(4)));
typedef short short8 __attribute__((ext_vector_type(8)));
typedef unsigned uint4v __attribute__((ext_vector_type(4)));

__device__ __forceinline__ ushort f2bf(float x) {            // fp32 -> bf16 RNE
    unsigned u = __float_as_uint(x);
    return (ushort)((u + 0x7fffu + ((u >> 16) & 1u)) >> 16);
}
__device__ __forceinline__ float bf2f(ushort h) {
    return __uint_as_float(((unsigned)h) << 16);
}

// ---------------- pass 1: coarse partition ----------------
__global__ __launch_bounds__(256) void p1_histo(const int* __restrict__ dst, int E,
                                                int* __restrict__ bhist) {
    __shared__ int h[NB];
    int t = threadIdx.x, blk = blockIdx.x;
    h[t] = 0; __syncthreads();
    int per = (E + NB - 1) / NB;
    int s = blk * per, e = min(E, s + per);
    for (int i = s + t; i < e; i += 256) atomicAdd(&h[dst[i] / GROUP], 1);
    __syncthreads();
    bhist[t * NB + blk] = h[t];          // bucket-major [bucket][block]
}

// 256 blocks: block b exclusive-scans row b (over block index), writes rowtot[b].
__global__ __launch_bounds__(256) void p1_scanrow(int* __restrict__ bhist,
                                                  int* __restrict__ rowtot) {
    __shared__ int lds[256];
    int b = blockIdx.x, t = threadIdx.x;
    int v = bhist[b * NB + t];
    lds[t] = v; __syncthreads();
    for (int off = 1; off < 256; off <<= 1) {
        int x = (t >= off) ? lds[t - off] : 0;
        __syncthreads();
        lds[t] += x;
        __syncthreads();
    }
    bhist[b * NB + t] = lds[t] - v;      // exclusive within bucket row
    if (t == 255) rowtot[b] = lds[255];
}

// 1 block: exclusive scan of 256 bucket totals -> bktBase[0..256].
__global__ __launch_bounds__(256) void p1_scantot(const int* __restrict__ rowtot,
                                                  int* __restrict__ bktBase) {
    __shared__ int lds[256];
    int t = threadIdx.x;
    int v = rowtot[t];
    lds[t] = v; __syncthreads();
    for (int off = 1; off < 256; off <<= 1) {
        int x = (t >= off) ? lds[t - off] : 0;
        __syncthreads();
        lds[t] += x;
        __syncthreads();
    }
    bktBase[t] = lds[t] - v;
    if (t == 255) bktBase[NB] = lds[255];
}

// Scatter packed (dloc<<17 | src) into coarse-bucket regions of `pairs`.
__global__ __launch_bounds__(256) void p1_scatter(const int* __restrict__ src,
                                                  const int* __restrict__ dst, int E,
                                                  const int* __restrict__ bhist,
                                                  const int* __restrict__ bktBase,
                                                  int* __restrict__ pairs) {
    __shared__ int loff[NB];
    int t = threadIdx.x, blk = blockIdx.x;
    loff[t] = bhist[t * NB + blk] + bktBase[t]; __syncthreads();
    int per = (E + NB - 1) / NB;
    int s = blk * per, e = min(E, s + per);
    for (int i = s + t; i < e; i += 256) {
        int d = dst[i];
        int b = d / GROUP;
        int pos = atomicAdd(&loff[b], 1);
        pairs[pos] = ((d - b * GROUP) << 17) | src[i];
    }
}

// ---------------- pass 2: fine histogram -> deg, offs, norm (all fused) ----------------
__global__ __launch_bounds__(256) void p2_degoffs(const int* __restrict__ pairs,
                                                  const int* __restrict__ bktBase,
                                                  int* __restrict__ deg,
                                                  int* __restrict__ offs,
                                                  float* __restrict__ norm) {
    __shared__ int h[512];            // GROUP=391 padded to 512
    __shared__ int ssum[256];
    int t = threadIdx.x, b = blockIdx.x;
    int lo = b * GROUP;
    int cnt = min(GROUP, N_NODES - lo);
    for (int i = t; i < 512; i += 256) h[i] = 0;
    __syncthreads();
    int s0 = bktBase[b], s1 = bktBase[b + 1];
    for (int i = s0 + t; i < s1; i += 256) atomicAdd(&h[pairs[i] >> 17], 1);
    __syncthreads();
    int v0 = h[2 * t], v1 = h[2 * t + 1];
    int s = v0 + v1;
    ssum[t] = s; __syncthreads();
    for (int off = 1; off < 256; off <<= 1) {
        int x = (t >= off) ? ssum[t - off] : 0;
        __syncthreads();
        ssum[t] += x;
        __syncthreads();
    }
    int pre = ssum[t] - s;            // exclusive prefix of element 2t
    if (2 * t < cnt) {
        int node = lo + 2 * t;
        deg[node] = v0;
        offs[node] = s0 + pre;
        norm[node] = rsqrtf(fmaxf((float)v0, 1.0f));
    }
    if (2 * t + 1 < cnt) {
        int node = lo + 2 * t + 1;
        deg[node] = v1;
        offs[node] = s0 + pre + v0;
        norm[node] = rsqrtf(fmaxf((float)v1, 1.0f));
    }
}

// Per-bucket scatter of src into its contiguous esrc window, staged in LDS.
__global__ __launch_bounds__(256) void p2_scatter(const int* __restrict__ pairs,
                                                  const int* __restrict__ bktBase,
                                                  const int* __restrict__ offs, int E,
                                                  int* __restrict__ esrc) {
    __shared__ int loffs[GROUP];
    __shared__ int lcur[GROUP];
    __shared__ int sbuf[CAP];
    int t = threadIdx.x, b = blockIdx.x;
    int lo = b * GROUP;
    int cnt = min(GROUP, N_NODES - lo);
    int base = bktBase[b];
    int end  = bktBase[b + 1];
    int wsize = end - base;
    for (int i = t; i < cnt; i += 256) { loffs[i] = offs[lo + i] - base; lcur[i] = 0; }
    __syncthreads();
    bool fits = (wsize <= CAP);
    for (int i = base + t; i < end; i += 256) {
        int p = pairs[i];
        int dl = p >> 17;
        int sv = p & 0x1FFFF;
        int pos = loffs[dl] + atomicAdd(&lcur[dl], 1);
        if (fits) sbuf[pos] = sv; else esrc[base + pos] = sv;
    }
    __syncthreads();
    if (fits)
        for (int i = t; i < wsize; i += 256) esrc[base + i] = sbuf[i];
}

// ---------------- feat*norm -> bf16 table ----------------
__global__ void k_featbf(const float* __restrict__ feat, const float* __restrict__ norm,
                         unsigned* __restrict__ ft, int total) {
    int i = blockIdx.x * blockDim.x + threadIdx.x;   // one uint = 2 bf16 = 2 floats
    if (i < total) {
        float w = norm[i >> 6];
        float2 v = ((const float2*)feat)[i];
        ft[i] = (unsigned)f2bf(v.x * w) | ((unsigned)f2bf(v.y * w) << 16);
    }
}

// ---------------- gather: 4 edges per wave, 16B/lane loads ----------------
template<bool OUT_BF>
__global__ __launch_bounds__(256) void k_gather4(const unsigned* __restrict__ ft,
                                                 const int* __restrict__ offs,
                                                 const int* __restrict__ deg,
                                                 const int* __restrict__ esrc,
                                                 void* __restrict__ out) {
    int gtid = blockIdx.x * blockDim.x + threadIdx.x;
    int node = gtid >> 6;
    if (node >= N_NODES) return;
    int lane = gtid & 63;
    int g  = lane >> 4;       // edge subgroup 0..3
    int sl = lane & 15;       // 16 lanes x uint4 = 256B row
    int start = offs[node];
    int cnt   = deg[node];
    int last  = start + cnt - 1;
    float acc[8] = {0.f, 0.f, 0.f, 0.f, 0.f, 0.f, 0.f, 0.f};
    const uint4v* ftv = (const uint4v*)ft;
    for (int j = 0; j < cnt; j += 4) {
        int idx = start + j + g;
        int s = esrc[min(idx, last)];
        float w = (j + g < cnt) ? 1.0f : 0.0f;        // norm pre-folded into ft
        uint4v u = ftv[(size_t)s * 16 + sl];
        #pragma unroll
        for (int q = 0; q < 4; ++q) {
            unsigned uu = u[q];
            acc[q * 2]     = fmaf(__uint_as_float(uu << 16),          w, acc[q * 2]);
            acc[q * 2 + 1] = fmaf(__uint_as_float(uu & 0xffff0000u),  w, acc[q * 2 + 1]);
        }
    }
    #pragma unroll
    for (int q = 0; q < 8; ++q) {
        acc[q] += __shfl_xor(acc[q], 16, 64);
        acc[q] += __shfl_xor(acc[q], 32, 64);
    }
    if (OUT_BF) {
        if (g == 0) {
            uint4v o;
            #pragma unroll
            for (int q = 0; q < 4; ++q)
                o[q] = (unsigned)f2bf(acc[q * 2]) | ((unsigned)f2bf(acc[q * 2 + 1]) << 16);
            ((uint4v*)out)[(size_t)node * 16 + sl] = o;
        }
    } else {
        float2 o = {acc[g * 2], acc[g * 2 + 1]};
        ((float2*)out)[(size_t)node * 64 + sl * 4 + g] = o;
    }
}

// ---------------- gather (fp32 feat) fallback tier ----------------
__global__ __launch_bounds__(256) void k_gather(const float* __restrict__ feat,
                                                const float* __restrict__ norm,
                                                const int* __restrict__ offs,
                                                const int* __restrict__ deg,
                                                const int* __restrict__ esrc,
                                                float* __restrict__ agg) {
    int gtid = blockIdx.x * blockDim.x + threadIdx.x;
    int node = gtid >> 6;
    int lane = gtid & 63;
    if (node >= N_NODES) return;
    int start = offs[node];
    int cnt   = deg[node];
    float2 acc = {0.f, 0.f};
    const float2* feat2 = (const float2*)feat;
    int j = 0;
    for (; j + 2 <= cnt; j += 2) {
        int s0 = esrc[start + j];
        int s1 = esrc[start + j + 1];
        float n0 = norm[s0], n1 = norm[s1];
        float2 v0 = feat2[(size_t)s0 * 64 + lane];
        float2 v1 = feat2[(size_t)s1 * 64 + lane];
        acc.x = fmaf(v0.x, n0, acc.x); acc.y = fmaf(v0.y, n0, acc.y);
        acc.x = fmaf(v1.x, n1, acc.x); acc.y = fmaf(v1.y, n1, acc.y);
    }
    if (j < cnt) {
        int s0 = esrc[start + j];
        float n0 = norm[s0];
        float2 v0 = feat2[(size_t)s0 * 64 + lane];
        acc.x = fmaf(v0.x, n0, acc.x); acc.y = fmaf(v0.y, n0, acc.y);
    }
    ((float2*)agg)[(size_t)node * 64 + lane] = acc;
}

// ---------------- W pack: fragment-order bf16 hi/lo ----------------
__global__ void k_wpack(const float* __restrict__ W, ushort* __restrict__ whi,
                        ushort* __restrict__ wlo) {
    int p = blockIdx.x * blockDim.x + threadIdx.x;
    if (p >= 16384) return;
    int i  = p & 7;
    int l  = (p >> 3) & 63;
    int kt = (p >> 9) & 3;
    int ct = (p >> 11);
    int k = kt * 32 + (l >> 4) * 8 + i;
    int n = ct * 16 + (l & 15);
    float x = W[k * 128 + n];
    ushort h = f2bf(x);
    whi[p] = h;
    wlo[p] = f2bf(x - bf2f(h));
}

// ---------------- GEMM, A = bf16 agg (tier A2) ----------------
__global__ __launch_bounds__(256) void k_gemm_bf(const ushort* __restrict__ aggbf,
                                                 const ushort* __restrict__ whi,
                                                 const ushort* __restrict__ wlo,
                                                 const float* __restrict__ bias,
                                                 const float* __restrict__ norm,
                                                 float* __restrict__ out) {
    __shared__ ushort sH[16384];
    __shared__ ushort sL[16384];
    {
        const short8* gh = (const short8*)whi;
        const short8* gl = (const short8*)wlo;
        short8* lh = (short8*)sH;
        short8* ll = (short8*)sL;
        for (int i = threadIdx.x; i < 2048; i += 256) { lh[i] = gh[i]; ll[i] = gl[i]; }
    }
    __syncthreads();

    const int lane = threadIdx.x & 63;
    const int wid  = threadIdx.x >> 6;
    const int rsub = lane & 15;
    const int kgrp = lane >> 4;

    const short8* BH = (const short8*)sH;
    const short8* BL = (const short8*)sL;

    const int nstrips = N_NODES / 16;
    for (int strip = blockIdx.x * 4 + wid; strip < nstrips; strip += gridDim.x * 4) {
        const int row0 = strip * 16;
        const ushort* arow = aggbf + (size_t)(row0 + rsub) * D + kgrp * 8;
        short8 a[4];
        #pragma unroll
        for (int kt = 0; kt < 4; ++kt) a[kt] = *(const short8*)(arow + kt * 32);
        float nr[4];
        #pragma unroll
        for (int r = 0; r < 4; ++r) nr[r] = norm[row0 + kgrp * 4 + r];

        #pragma unroll
        for (int ct = 0; ct < 8; ++ct) {
            f32x4 acc = {0.f, 0.f, 0.f, 0.f};
            #pragma unroll
            for (int kt = 0; kt < 4; ++kt) {
                acc = __builtin_amdgcn_mfma_f32_16x16x32_bf16(a[kt], BH[(ct * 4 + kt) * 64 + lane], acc, 0, 0, 0);
                acc = __builtin_amdgcn_mfma_f32_16x16x32_bf16(a[kt], BL[(ct * 4 + kt) * 64 + lane], acc, 0, 0, 0);
            }
            const float bc = bias[ct * 16 + rsub];
            float* ocol = out + (size_t)row0 * D + ct * 16 + rsub;
            #pragma unroll
            for (int r = 0; r < 4; ++r) {
                int row = kgrp * 4 + r;
                ocol[(size_t)row * D] = acc[r] * nr[r] + bc;
            }
        }
    }
}

// ---------------- GEMM, A = fp32 agg in-place (tier A/B): split-bf16 A ----------------
__global__ __launch_bounds__(256) void k_gemm_mfma(float* __restrict__ io,
                                                   const ushort* __restrict__ whi,
                                                   const ushort* __restrict__ wlo,
                                                   const float* __restrict__ bias,
                                                   const float* __restrict__ norm) {
    __shared__ ushort sH[16384];
    __shared__ ushort sL[16384];
    {
        const short8* gh = (const short8*)whi;
        const short8* gl = (const short8*)wlo;
        short8* lh = (short8*)sH;
        short8* ll = (short8*)sL;
        for (int i = threadIdx.x; i < 2048; i += 256) { lh[i] = gh[i]; ll[i] = gl[i]; }
    }
    __syncthreads();

    const int lane = threadIdx.x & 63;
    const int wid  = threadIdx.x >> 6;
    const int rsub = lane & 15;
    const int kgrp = lane >> 4;

    const short8* BH = (const short8*)sH;
    const short8* BL = (const short8*)sL;

    const int nstrips = N_NODES / 16;
    for (int strip = blockIdx.x * 4 + wid; strip < nstrips; strip += gridDim.x * 4) {
        const int row0 = strip * 16;
        const float* arow = io + (size_t)(row0 + rsub) * D + kgrp * 8;
        short8 ahi[4], alo[4];
        #pragma unroll
        for (int kt = 0; kt < 4; ++kt) {
            f32x4 x0 = *(const f32x4*)(arow + kt * 32);
            f32x4 x1 = *(const f32x4*)(arow + kt * 32 + 4);
            short8 h, l;
            #pragma unroll
            for (int j = 0; j < 4; ++j) {
                ushort h0 = f2bf(x0[j]);
                h[j]     = (short)h0;  l[j]     = (short)f2bf(x0[j] - bf2f(h0));
                ushort h1 = f2bf(x1[j]);
                h[j + 4] = (short)h1;  l[j + 4] = (short)f2bf(x1[j] - bf2f(h1));
            }
            ahi[kt] = h; alo[kt] = l;
        }
        float nr[4];
        #pragma unroll
        for (int r = 0; r < 4; ++r) nr[r] = norm[row0 + kgrp * 4 + r];

        #pragma unroll
        for (int ct = 0; ct < 8; ++ct) {
            f32x4 acc = {0.f, 0.f, 0.f, 0.f};
            #pragma unroll
            for (int kt = 0; kt < 4; ++kt) {
                short8 bh = BH[(ct * 4 + kt) * 64 + lane];
                short8 bl = BL[(ct * 4 + kt) * 64 + lane];
                acc = __builtin_amdgcn_mfma_f32_16x16x32_bf16(ahi[kt], bh, acc, 0, 0, 0);
                acc = __builtin_amdgcn_mfma_f32_16x16x32_bf16(alo[kt], bh, acc, 0, 0, 0);
                acc = __builtin_amdgcn_mfma_f32_16x16x32_bf16(ahi[kt], bl, acc, 0, 0, 0);
            }
            const float bc = bias[ct * 16 + rsub];
            float* ocol = io + (size_t)row0 * D + ct * 16 + rsub;
            #pragma unroll
            for (int r = 0; r < 4; ++r) {
                int row = kgrp * 4 + r;
                ocol[(size_t)row * D] = acc[r] * nr[r] + bc;
            }
        }
    }
}

// ---------------- last-resort fallback (atomic scatter) ----------------
__global__ void k_scatter(const float* __restrict__ feat, const int* __restrict__ src,
                          const int* __restrict__ dst, const float* __restrict__ norm,
                          int E, float* __restrict__ agg) {
    long long gtid = (long long)blockIdx.x * blockDim.x + threadIdx.x;
    int e    = (int)(gtid >> 6);
    int lane = (int)(gtid & 63);
    if (e >= E) return;
    int s = src[e];
    int t = dst[e];
    float ns = norm[s];
    float2 v = ((const float2*)(feat + (size_t)s * D))[lane];
    float* arow = agg + (size_t)t * D + lane * 2;
    atomicAdd(arow + 0, v.x * ns);
    atomicAdd(arow + 1, v.y * ns);
}
__global__ void k_deg_f(const int* __restrict__ dst, int E, float* __restrict__ deg) {
    int i = blockIdx.x * blockDim.x + threadIdx.x;
    if (i < E) atomicAdd(deg + dst[i], 1.0f);
}
__global__ void k_norm_f(float* __restrict__ dn) {
    int i = blockIdx.x * blockDim.x + threadIdx.x;
    if (i < N_NODES) dn[i] = rsqrtf(fmaxf(dn[i], 1.0f));
}
__global__ __launch_bounds__(256) void k_gemm(float* __restrict__ io,
                                              const float* __restrict__ W,
                                              const float* __restrict__ bias,
                                              const float* __restrict__ norm) {
    __shared__ float sW[D * D];
    __shared__ float srow[2][D];
    for (int i = threadIdx.x; i < D * D; i += 256) sW[i] = W[i];
    const int r = threadIdx.x >> 7;
    const int c = threadIdx.x & 127;
    const float bc = bias[c];
    const int npairs = N_NODES / 2;
    for (int rp = blockIdx.x; rp < npairs; rp += gridDim.x) {
        __syncthreads();
        const int row = rp * 2 + r;
        srow[r][c] = io[(size_t)row * D + c];
        __syncthreads();
        float acc = 0.f;
        #pragma unroll 8
        for (int k = 0; k < D; ++k)
            acc = fmaf(srow[r][k], sW[k * D + c], acc);
        io[(size_t)row * D + c] = acc * norm[row] + bc;
    }
}

extern "C" void kernel_launch(void* const* d_in, const int* in_sizes, int n_in,
                              void* d_out, int out_size, void* d_ws, size_t ws_size,
                              hipStream_t stream) {
    const float* feat   = (const float*)d_in[0];
    const float* weight = (const float*)d_in[1];
    const float* bias   = (const float*)d_in[2];
    const int*   src    = (const int*)d_in[3];
    const int*   dst    = (const int*)d_in[4];
    const int E = in_sizes[3];

    float* agg   = (float*)d_out;
    int*   pairs = (int*)d_out;    // d_out doubles as pairs scratch (dead before agg is written)

    // ---- workspace allocator (64B aligned) ----
    uintptr_t cur = (uintptr_t)d_ws;
    auto take = [&](size_t bytes) -> void* {
        uintptr_t r = (cur + 63) & ~(uintptr_t)63;
        cur = r + bytes;
        return (void*)r;
    };

    size_t S_ft   = (size_t)N_NODES * 64 * 4;    // 25.6 MB
    size_t S_agg  = (size_t)N_NODES * D * 2;     // 25.6 MB
    size_t S_small = (size_t)(3 * N_NODES + 256 + NB * NB + NB + 1 + E) * 4 + 65536 + 16 * 64;
    size_t needB  = S_small;
    size_t needA  = S_small + S_ft + 64;
    size_t needA2 = needA + S_agg + 64;

    bool tierA2 = ws_size >= needA2;
    bool tierA  = ws_size >= needA;
    bool tierB  = ws_size >= needB;

    unsigned* ft    = (tierA || tierA2) ? (unsigned*)take(S_ft) : nullptr;
    ushort*   aggbf = tierA2 ? (ushort*)take(S_agg) : nullptr;
    float*    norm    = (float*)take((size_t)N_NODES * 4);
    int*      deg     = (int*)take((size_t)N_NODES * 4);
    int*      offs    = (int*)take((size_t)N_NODES * 4);
    int*      rowtot  = (int*)take(256 * 4);
    int*      bhist   = (int*)take((size_t)NB * NB * 4);
    int*      bktBase = (int*)take((size_t)(NB + 1) * 4);
    int*      esrc    = (int*)take((size_t)E * 4);
    ushort*   whi     = (ushort*)take(16384 * 2);
    ushort*   wlo     = (ushort*)take(16384 * 2);

    if (tierB) {
        k_wpack<<<64, 256, 0, stream>>>(weight, whi, wlo);
        // deterministic two-level counting sort (all-parallel scans)
        p1_histo<<<NB, 256, 0, stream>>>(dst, E, bhist);
        p1_scanrow<<<NB, 256, 0, stream>>>(bhist, rowtot);
        p1_scantot<<<1, 256, 0, stream>>>(rowtot, bktBase);
        p1_scatter<<<NB, 256, 0, stream>>>(src, dst, E, bhist, bktBase, pairs);
        p2_degoffs<<<NB, 256, 0, stream>>>(pairs, bktBase, deg, offs, norm);
        p2_scatter<<<NB, 256, 0, stream>>>(pairs, bktBase, offs, E, esrc);

        long long gthreads = (long long)N_NODES * 64;
        int gblocks = (int)((gthreads + 255) / 256);
        if (tierA || tierA2) {
            k_featbf<<<(N_NODES * 64 + 255) / 256, 256, 0, stream>>>(feat, norm, ft, N_NODES * 64);
            if (tierA2) {
                k_gather4<true><<<gblocks, 256, 0, stream>>>(ft, offs, deg, esrc, aggbf);
                k_gemm_bf<<<1024, 256, 0, stream>>>(aggbf, whi, wlo, bias, norm, (float*)d_out);
            } else {
                k_gather4<false><<<gblocks, 256, 0, stream>>>(ft, offs, deg, esrc, agg);
                k_gemm_mfma<<<1024, 256, 0, stream>>>(agg, whi, wlo, bias, norm);
            }
        } else {
            k_gather<<<gblocks, 256, 0, stream>>>(feat, norm, offs, deg, esrc, agg);
            k_gemm_mfma<<<1024, 256, 0, stream>>>(agg, whi, wlo, bias, norm);
        }
    } else {
        // last-resort: atomic scatter path
        hipMemsetAsync(d_out, 0, (size_t)N_NODES * D * sizeof(float), stream);
        hipMemsetAsync(norm, 0, (size_t)N_NODES * sizeof(float), stream);
        k_deg_f<<<(E + 255) / 256, 256, 0, stream>>>(dst, E, (float*)norm);
        k_norm_f<<<(N_NODES + 255) / 256, 256, 0, stream>>>((float*)norm);
        long long sthreads = (long long)E * 64;
        k_scatter<<<(int)((sthreads + 255) / 256), 256, 0, stream>>>(feat, src, dst, norm, E, agg);
        k_gemm<<<4096, 256, 0, stream>>>(agg, weight, bias, norm);
    }
}

// Round 8
// 140.896 us; speedup vs baseline: 11.4553x; 1.1405x over previous
//
#include <hip/hip_runtime.h>

// GraphConv: counting-sort CSR + normed-bf16 gather (8 edges/wave-iter) + bf16-A MFMA GEMM.
// Round 7: round-6 design with the compile fix (cast aggbf ushort* -> unsigned* at k_gather8 call).
//   (a) gather8 doubles memory-level parallelism (2 uint4 loads in flight/wave);
//   (b) fused sort pipeline, 7 dispatches total;
//   (c) featbf widened to float4/uint2.

constexpr int N_NODES = 100000;
constexpr int D = 128;
constexpr int NB = 256;                        // coarse buckets
constexpr int GROUP = (N_NODES + NB - 1) / NB; // 391 nodes per bucket
constexpr int CAP = 14336;                     // LDS esrc staging capacity (56KB)

typedef float f32x4 __attribute__((ext_vector_type(4)));
typedef short short8 __attribute__((ext_vector_type(8)));
typedef unsigned uint4v __attribute__((ext_vector_type(4)));

__device__ __forceinline__ ushort f2bf(float x) {            // fp32 -> bf16 RNE
    unsigned u = __float_as_uint(x);
    return (ushort)((u + 0x7fffu + ((u >> 16) & 1u)) >> 16);
}
__device__ __forceinline__ float bf2f(ushort h) {
    return __uint_as_float(((unsigned)h) << 16);
}

// ---------------- pass 1: coarse histogram (+ W pack folded into blocks 0..63) ----------------
__global__ __launch_bounds__(256) void p1_histo(const int* __restrict__ dst, int E,
                                                int* __restrict__ bhist,
                                                const float* __restrict__ W,
                                                ushort* __restrict__ whi,
                                                ushort* __restrict__ wlo) {
    __shared__ int h[NB];
    int t = threadIdx.x, blk = blockIdx.x;
    h[t] = 0;
    if (blk < 64) {                       // fold k_wpack: 64*256 = 16384 elements
        int p = blk * 256 + t;
        int i  = p & 7;
        int l  = (p >> 3) & 63;
        int kt = (p >> 9) & 3;
        int ct = (p >> 11);
        int k = kt * 32 + (l >> 4) * 8 + i;
        int n = ct * 16 + (l & 15);
        float x = W[k * 128 + n];
        ushort hh = f2bf(x);
        whi[p] = hh;
        wlo[p] = f2bf(x - bf2f(hh));
    }
    __syncthreads();
    int per = (E + NB - 1) / NB;
    int s = blk * per, e = min(E, s + per);
    for (int i = s + t; i < e; i += 256) atomicAdd(&h[dst[i] / GROUP], 1);
    __syncthreads();
    bhist[t * NB + blk] = h[t];          // bucket-major [bucket][chunk]
}

// 256 blocks: block b exclusive-scans bucket row b over chunks; writes rowtot[b].
__global__ __launch_bounds__(256) void p1_scanrow(int* __restrict__ bhist,
                                                  int* __restrict__ rowtot) {
    __shared__ int lds[256];
    int b = blockIdx.x, t = threadIdx.x;
    int v = bhist[b * NB + t];
    lds[t] = v; __syncthreads();
    for (int off = 1; off < 256; off <<= 1) {
        int x = (t >= off) ? lds[t - off] : 0;
        __syncthreads();
        lds[t] += x;
        __syncthreads();
    }
    bhist[b * NB + t] = lds[t] - v;      // exclusive within bucket row
    if (t == 255) rowtot[b] = lds[255];
}

// Scatter packed (dloc<<17 | src) into coarse-bucket regions; bktBase recomputed in LDS.
__global__ __launch_bounds__(256) void p1_scatter(const int* __restrict__ src,
                                                  const int* __restrict__ dst, int E,
                                                  const int* __restrict__ bhist,
                                                  const int* __restrict__ rowtot,
                                                  int* __restrict__ pairs) {
    __shared__ int loff[NB];
    __shared__ int bb[NB];
    int t = threadIdx.x, blk = blockIdx.x;
    int rv = rowtot[t];
    bb[t] = rv; __syncthreads();
    for (int off = 1; off < 256; off <<= 1) {
        int x = (t >= off) ? bb[t - off] : 0;
        __syncthreads();
        bb[t] += x;
        __syncthreads();
    }
    loff[t] = bhist[t * NB + blk] + bb[t] - rv;   // chunk offset + bucket base
    __syncthreads();
    int per = (E + NB - 1) / NB;
    int s = blk * per, e = min(E, s + per);
    for (int i = s + t; i < e; i += 256) {
        int d = dst[i];
        int b = d / GROUP;
        int pos = atomicAdd(&loff[b], 1);
        pairs[pos] = ((d - b * GROUP) << 17) | src[i];
    }
}

// ---------------- pass 2 (fused): fine histogram -> deg/offs/norm, then esrc scatter ----------------
__global__ __launch_bounds__(256) void p2_all(const int* __restrict__ pairs,
                                              const int* __restrict__ rowtot,
                                              int* __restrict__ deg,
                                              int* __restrict__ offs,
                                              float* __restrict__ norm,
                                              int* __restrict__ esrc) {
    __shared__ int h[512];            // fine histogram, then in-bucket position counters
    __shared__ int ssum[256];
    __shared__ int bb[256];
    __shared__ int sbuf[CAP];
    int t = threadIdx.x, b = blockIdx.x;
    int lo = b * GROUP;
    int cnt = min(GROUP, N_NODES - lo);

    // recompute bucket bases from rowtot (inclusive scan)
    int rv = rowtot[t];
    bb[t] = rv;
    h[t] = 0; h[t + 256] = 0;
    __syncthreads();
    for (int off = 1; off < 256; off <<= 1) {
        int x = (t >= off) ? bb[t - off] : 0;
        __syncthreads();
        bb[t] += x;
        __syncthreads();
    }
    int s1 = bb[b];
    int s0 = s1 - rowtot[b];
    __syncthreads();

    // fine histogram over this bucket's pairs
    for (int i = s0 + t; i < s1; i += 256) atomicAdd(&h[pairs[i] >> 17], 1);
    __syncthreads();

    // scan pairs of counts -> deg/offs/norm
    int v0 = h[2 * t], v1 = h[2 * t + 1];
    int s = v0 + v1;
    ssum[t] = s; __syncthreads();
    for (int off = 1; off < 256; off <<= 1) {
        int x = (t >= off) ? ssum[t - off] : 0;
        __syncthreads();
        ssum[t] += x;
        __syncthreads();
    }
    int pre = ssum[t] - s;            // exclusive prefix of node 2t within bucket
    if (2 * t < cnt) {
        int node = lo + 2 * t;
        deg[node] = v0;
        offs[node] = s0 + pre;
        norm[node] = rsqrtf(fmaxf((float)v0, 1.0f));
    }
    if (2 * t + 1 < cnt) {
        int node = lo + 2 * t + 1;
        deg[node] = v1;
        offs[node] = s0 + pre + v0;
        norm[node] = rsqrtf(fmaxf((float)v1, 1.0f));
    }
    __syncthreads();
    // reuse h as running in-bucket position counters
    h[2 * t] = pre;
    h[2 * t + 1] = pre + v0;
    __syncthreads();

    int wsize = s1 - s0;
    bool fits = (wsize <= CAP);
    for (int i = s0 + t; i < s1; i += 256) {
        int p = pairs[i];
        int dl = p >> 17;
        int sv = p & 0x1FFFF;
        int pos = atomicAdd(&h[dl], 1);
        if (fits) sbuf[pos] = sv; else esrc[s0 + pos] = sv;
    }
    __syncthreads();
    if (fits)
        for (int i = t; i < wsize; i += 256) esrc[s0 + i] = sbuf[i];
}

// ---------------- feat*norm -> bf16 table (float4 in, uint2 out) ----------------
__global__ void k_featbf(const float* __restrict__ feat, const float* __restrict__ norm,
                         uint2* __restrict__ ft2, int total) {
    int i = blockIdx.x * blockDim.x + threadIdx.x;   // one uint2 = 4 bf16 = 4 floats
    if (i < total) {
        float w = norm[i >> 5];
        f32x4 v = ((const f32x4*)feat)[i];
        uint2 o;
        o.x = (unsigned)f2bf(v[0] * w) | ((unsigned)f2bf(v[1] * w) << 16);
        o.y = (unsigned)f2bf(v[2] * w) | ((unsigned)f2bf(v[3] * w) << 16);
        ft2[i] = o;
    }
}

// ---------------- gather: 8 edges per wave-iteration, 2x uint4 loads in flight ----------------
__global__ __launch_bounds__(256) void k_gather8(const unsigned* __restrict__ ft,
                                                 const int* __restrict__ offs,
                                                 const int* __restrict__ deg,
                                                 const int* __restrict__ esrc,
                                                 unsigned* __restrict__ outbf) {
    int gtid = blockIdx.x * blockDim.x + threadIdx.x;
    int node = gtid >> 6;
    if (node >= N_NODES) return;
    int lane = gtid & 63;
    int g  = lane >> 4;       // edge subgroup 0..3
    int sl = lane & 15;       // 16 lanes x uint4 = 256B row
    int start = offs[node];
    int cnt   = deg[node];
    int last  = start + cnt - 1;
    float acc[8] = {0.f, 0.f, 0.f, 0.f, 0.f, 0.f, 0.f, 0.f};
    const uint4v* ftv = (const uint4v*)ft;
    for (int j = 0; j < cnt; j += 8) {
        int i0 = start + j + g;
        int i1 = start + j + 4 + g;
        int s0v = esrc[min(i0, last)];
        int s1v = esrc[min(i1, last)];
        float w0 = (j + g     < cnt) ? 1.0f : 0.0f;   // norm pre-folded into ft
        float w1 = (j + 4 + g < cnt) ? 1.0f : 0.0f;
        uint4v u0 = ftv[(size_t)s0v * 16 + sl];
        uint4v u1 = ftv[(size_t)s1v * 16 + sl];
        #pragma unroll
        for (int q = 0; q < 4; ++q) {
            unsigned a = u0[q];
            acc[q * 2]     = fmaf(__uint_as_float(a << 16),         w0, acc[q * 2]);
            acc[q * 2 + 1] = fmaf(__uint_as_float(a & 0xffff0000u), w0, acc[q * 2 + 1]);
        }
        #pragma unroll
        for (int q = 0; q < 4; ++q) {
            unsigned a = u1[q];
            acc[q * 2]     = fmaf(__uint_as_float(a << 16),         w1, acc[q * 2]);
            acc[q * 2 + 1] = fmaf(__uint_as_float(a & 0xffff0000u), w1, acc[q * 2 + 1]);
        }
    }
    #pragma unroll
    for (int q = 0; q < 8; ++q) {
        acc[q] += __shfl_xor(acc[q], 16, 64);
        acc[q] += __shfl_xor(acc[q], 32, 64);
    }
    if (g == 0) {
        uint4v o;
        #pragma unroll
        for (int q = 0; q < 4; ++q)
            o[q] = (unsigned)f2bf(acc[q * 2]) | ((unsigned)f2bf(acc[q * 2 + 1]) << 16);
        ((uint4v*)outbf)[(size_t)node * 16 + sl] = o;
    }
}

// ---------------- GEMM, A = bf16 agg: out = aggbf @ (Whi+Wlo) * norm + bias ----------------
__global__ __launch_bounds__(256) void k_gemm_bf(const ushort* __restrict__ aggbf,
                                                 const ushort* __restrict__ whi,
                                                 const ushort* __restrict__ wlo,
                                                 const float* __restrict__ bias,
                                                 const float* __restrict__ norm,
                                                 float* __restrict__ out) {
    __shared__ ushort sH[16384];
    __shared__ ushort sL[16384];
    {
        const short8* gh = (const short8*)whi;
        const short8* gl = (const short8*)wlo;
        short8* lh = (short8*)sH;
        short8* ll = (short8*)sL;
        for (int i = threadIdx.x; i < 2048; i += 256) { lh[i] = gh[i]; ll[i] = gl[i]; }
    }
    __syncthreads();

    const int lane = threadIdx.x & 63;
    const int wid  = threadIdx.x >> 6;
    const int rsub = lane & 15;
    const int kgrp = lane >> 4;

    const short8* BH = (const short8*)sH;
    const short8* BL = (const short8*)sL;

    const int nstrips = N_NODES / 16;
    for (int strip = blockIdx.x * 4 + wid; strip < nstrips; strip += gridDim.x * 4) {
        const int row0 = strip * 16;
        const ushort* arow = aggbf + (size_t)(row0 + rsub) * D + kgrp * 8;
        short8 a[4];
        #pragma unroll
        for (int kt = 0; kt < 4; ++kt) a[kt] = *(const short8*)(arow + kt * 32);
        float nr[4];
        #pragma unroll
        for (int r = 0; r < 4; ++r) nr[r] = norm[row0 + kgrp * 4 + r];

        #pragma unroll
        for (int ct = 0; ct < 8; ++ct) {
            f32x4 acc = {0.f, 0.f, 0.f, 0.f};
            #pragma unroll
            for (int kt = 0; kt < 4; ++kt) {
                acc = __builtin_amdgcn_mfma_f32_16x16x32_bf16(a[kt], BH[(ct * 4 + kt) * 64 + lane], acc, 0, 0, 0);
                acc = __builtin_amdgcn_mfma_f32_16x16x32_bf16(a[kt], BL[(ct * 4 + kt) * 64 + lane], acc, 0, 0, 0);
            }
            const float bc = bias[ct * 16 + rsub];
            float* ocol = out + (size_t)row0 * D + ct * 16 + rsub;
            #pragma unroll
            for (int r = 0; r < 4; ++r) {
                int row = kgrp * 4 + r;
                ocol[(size_t)row * D] = acc[r] * nr[r] + bc;
            }
        }
    }
}

// ---------------- last-resort fallback (atomic scatter) ----------------
__global__ void k_scatter(const float* __restrict__ feat, const int* __restrict__ src,
                          const int* __restrict__ dst, const float* __restrict__ norm,
                          int E, float* __restrict__ agg) {
    long long gtid = (long long)blockIdx.x * blockDim.x + threadIdx.x;
    int e    = (int)(gtid >> 6);
    int lane = (int)(gtid & 63);
    if (e >= E) return;
    int s = src[e];
    int t = dst[e];
    float ns = norm[s];
    float2 v = ((const float2*)(feat + (size_t)s * D))[lane];
    float* arow = agg + (size_t)t * D + lane * 2;
    atomicAdd(arow + 0, v.x * ns);
    atomicAdd(arow + 1, v.y * ns);
}
__global__ void k_deg_f(const int* __restrict__ dst, int E, float* __restrict__ deg) {
    int i = blockIdx.x * blockDim.x + threadIdx.x;
    if (i < E) atomicAdd(deg + dst[i], 1.0f);
}
__global__ void k_norm_f(float* __restrict__ dn) {
    int i = blockIdx.x * blockDim.x + threadIdx.x;
    if (i < N_NODES) dn[i] = rsqrtf(fmaxf(dn[i], 1.0f));
}
__global__ __launch_bounds__(256) void k_gemm(float* __restrict__ io,
                                              const float* __restrict__ W,
                                              const float* __restrict__ bias,
                                              const float* __restrict__ norm) {
    __shared__ float sW[D * D];
    __shared__ float srow[2][D];
    for (int i = threadIdx.x; i < D * D; i += 256) sW[i] = W[i];
    const int r = threadIdx.x >> 7;
    const int c = threadIdx.x & 127;
    const float bc = bias[c];
    const int npairs = N_NODES / 2;
    for (int rp = blockIdx.x; rp < npairs; rp += gridDim.x) {
        __syncthreads();
        const int row = rp * 2 + r;
        srow[r][c] = io[(size_t)row * D + c];
        __syncthreads();
        float acc = 0.f;
        #pragma unroll 8
        for (int k = 0; k < D; ++k)
            acc = fmaf(srow[r][k], sW[k * D + c], acc);
        io[(size_t)row * D + c] = acc * norm[row] + bc;
    }
}

extern "C" void kernel_launch(void* const* d_in, const int* in_sizes, int n_in,
                              void* d_out, int out_size, void* d_ws, size_t ws_size,
                              hipStream_t stream) {
    const float* feat   = (const float*)d_in[0];
    const float* weight = (const float*)d_in[1];
    const float* bias   = (const float*)d_in[2];
    const int*   src    = (const int*)d_in[3];
    const int*   dst    = (const int*)d_in[4];
    const int E = in_sizes[3];

    int* pairs = (int*)d_out;    // d_out doubles as pairs scratch (dead before output written)

    // ---- workspace allocator (64B aligned) ----
    uintptr_t cur = (uintptr_t)d_ws;
    auto take = [&](size_t bytes) -> void* {
        uintptr_t r = (cur + 63) & ~(uintptr_t)63;
        cur = r + bytes;
        return (void*)r;
    };

    size_t S_ft  = (size_t)N_NODES * 64 * 4;     // 25.6 MB
    size_t S_agg = (size_t)N_NODES * D * 2;      // 25.6 MB
    size_t need  = S_ft + S_agg +
                   (size_t)(3 * N_NODES + 256 + NB * NB + E) * 4 + 65536 + 1024;

    unsigned* ft     = (unsigned*)take(S_ft);
    ushort*   aggbf  = (ushort*)take(S_agg);
    float*    norm   = (float*)take((size_t)N_NODES * 4);
    int*      deg    = (int*)take((size_t)N_NODES * 4);
    int*      offs   = (int*)take((size_t)N_NODES * 4);
    int*      rowtot = (int*)take(256 * 4);
    int*      bhist  = (int*)take((size_t)NB * NB * 4);
    int*      esrc   = (int*)take((size_t)E * 4);
    ushort*   whi    = (ushort*)take(16384 * 2);
    ushort*   wlo    = (ushort*)take(16384 * 2);

    if (ws_size >= need) {
        p1_histo<<<NB, 256, 0, stream>>>(dst, E, bhist, weight, whi, wlo);
        p1_scanrow<<<NB, 256, 0, stream>>>(bhist, rowtot);
        p1_scatter<<<NB, 256, 0, stream>>>(src, dst, E, bhist, rowtot, pairs);
        p2_all<<<NB, 256, 0, stream>>>(pairs, rowtot, deg, offs, norm, esrc);
        k_featbf<<<(N_NODES * 32 + 255) / 256, 256, 0, stream>>>(feat, norm, (uint2*)ft, N_NODES * 32);
        long long gthreads = (long long)N_NODES * 64;
        k_gather8<<<(int)((gthreads + 255) / 256), 256, 0, stream>>>(ft, offs, deg, esrc, (unsigned*)aggbf);
        k_gemm_bf<<<1024, 256, 0, stream>>>(aggbf, whi, wlo, bias, norm, (float*)d_out);
    } else {
        // last-resort: atomic scatter path (fp32 end-to-end)
        float* agg = (float*)d_out;
        hipMemsetAsync(d_out, 0, (size_t)N_NODES * D * sizeof(float), stream);
        hipMemsetAsync(norm, 0, (size_t)N_NODES * sizeof(float), stream);
        k_deg_f<<<(E + 255) / 256, 256, 0, stream>>>(dst, E, (float*)norm);
        k_norm_f<<<(N_NODES + 255) / 256, 256, 0, stream>>>((float*)norm);
        long long sthreads = (long long)E * 64;
        k_scatter<<<(int)((sthreads + 255) / 256), 256, 0, stream>>>(feat, src, dst, (float*)norm, E, agg);
        k_gemm<<<4096, 256, 0, stream>>>(agg, weight, bias, (float*)norm);
    }
}